// Round 14
// baseline (350.299 us; speedup 1.0000x reference)
//
#include <hip/hip_runtime.h>
#include <math.h>

#define HEADS 8
#define DK 64
#define DMODEL 512
#define BATCH 2
#define SEQ 2048
#define BH (BATCH * HEADS)

using f32x4 = __attribute__((ext_vector_type(4))) float;
using s16x8 = __attribute__((ext_vector_type(8))) short;
using fp16x2 = __attribute__((ext_vector_type(2))) __fp16;  // cvt_pkrtz's type

union FragU {
  uint4 u;
  s16x8 s;
  unsigned short us[8];
};
union PkU {
  fp16x2 h;
  unsigned int u;
};

__device__ __forceinline__ unsigned short f32_to_bf16(float f) {
  unsigned int u = __float_as_uint(f);
  u += 0x7fffu + ((u >> 16) & 1u);
  return (unsigned short)(u >> 16);
}
__device__ __forceinline__ float bf16_to_f32(unsigned short h) {
  return __uint_as_float(((unsigned int)h) << 16);
}

// ---------------------------------------------------------------------------
// mask int32 [B][S][S] -> packed bits [B][S][S/32]. One block per row.
// ---------------------------------------------------------------------------
__global__ __launch_bounds__(256) void pack_mask_kernel(
    const int* __restrict__ mask, unsigned int* __restrict__ bits) {
  const size_t row = blockIdx.x;  // B*S = 4096 rows
  const int wv = threadIdx.x >> 6, lane = threadIdx.x & 63;
  #pragma unroll
  for (int i = 0; i < 8; ++i) {
    const int c = wv * 512 + i * 64 + lane;
    unsigned long long bal = __ballot(mask[row * SEQ + c] != 0);
    if (lane == 0) {
      bits[row * 64 + (c >> 5)] = (unsigned int)bal;
      bits[row * 64 + (c >> 5) + 1] = (unsigned int)(bal >> 32);
    }
  }
}

// ---------------------------------------------------------------------------
// W[512][512] f32 -> Wt hi/lo bf16 in [n][k] (transposed) layout.
// ---------------------------------------------------------------------------
__global__ __launch_bounds__(256) void wsplit_kernel(
    const float* __restrict__ W, unsigned short* __restrict__ WtHi,
    unsigned short* __restrict__ WtLo) {
  __shared__ float t[64][65];
  const int k0 = blockIdx.x * 64, n0 = blockIdx.y * 64;
  const int tid = threadIdx.x;
  const int r = tid >> 2, c = (tid & 3) * 16;
  #pragma unroll
  for (int e = 0; e < 4; ++e) {
    f32x4 v = *(const f32x4*)&W[(size_t)(k0 + r) * DMODEL + n0 + c + e * 4];
    #pragma unroll
    for (int j = 0; j < 4; ++j) t[r][c + e * 4 + j] = v[j];
  }
  __syncthreads();
  const int rn = tid >> 2, ck = (tid & 3) * 16;
  #pragma unroll
  for (int half = 0; half < 2; ++half) {
    FragU hi, lo;
    #pragma unroll
    for (int e = 0; e < 8; ++e) {
      float x = t[ck + half * 8 + e][rn];
      unsigned short h = f32_to_bf16(x);
      hi.us[e] = h;
      lo.us[e] = f32_to_bf16(x - bf16_to_f32(h));
    }
    const size_t o = (size_t)(n0 + rn) * DMODEL + k0 + ck + half * 8;
    *(uint4*)&WtHi[o] = hi.u;
    *(uint4*)&WtLo[o] = lo.u;
  }
}

// ---------------------------------------------------------------------------
// MFMA projection GEMM (R8 structure): B-tile LDS-staged, coalesced
// transposed output. All Y layouts FLAT [4096][512].
// MODE 1: Y -> bf16 hi/lo pair; MODE 2: Y -> bf16; MODE 3: X bf16, Y f32.
// ---------------------------------------------------------------------------
template <int MODE>
__global__ __launch_bounds__(256) void proj_mfma_kernel(
    const float* __restrict__ X, const unsigned short* __restrict__ X16,
    const unsigned short* __restrict__ WtHi,
    const unsigned short* __restrict__ WtLo, const float* __restrict__ bias,
    float* __restrict__ Yf, unsigned short* __restrict__ Yhi,
    unsigned short* __restrict__ Ylo) {
  __shared__ unsigned short BsHi[64][72];
  __shared__ unsigned short BsLo[64][72];
  const int tid = threadIdx.x, wv = tid >> 6, lane = tid & 63;
  const int lr = lane & 15, lg = lane >> 4;
  const int m0 = blockIdx.x * 64;
  const int mw = m0 + wv * 16;
  const int n0 = blockIdx.y * 64;

  f32x4 acc[4] = {};
  for (int k0 = 0; k0 < 512; k0 += 64) {
    FragU ah[2], al[2];
    #pragma unroll
    for (int dc = 0; dc < 2; ++dc) {
      const size_t xi = (size_t)(mw + lr) * DMODEL + k0 + dc * 32 + lg * 8;
      if (MODE == 3) {
        ah[dc].u = *(const uint4*)&X16[xi];
      } else {
        f32x4 x0 = *(const f32x4*)&X[xi];
        f32x4 x1 = *(const f32x4*)&X[xi + 4];
        #pragma unroll
        for (int t = 0; t < 4; ++t) {
          unsigned short h0 = f32_to_bf16(x0[t]);
          unsigned short h1 = f32_to_bf16(x1[t]);
          ah[dc].us[t] = h0;
          ah[dc].us[4 + t] = h1;
          al[dc].us[t] = f32_to_bf16(x0[t] - bf16_to_f32(h0));
          al[dc].us[4 + t] = f32_to_bf16(x1[t] - bf16_to_f32(h1));
        }
      }
    }
    __syncthreads();
    #pragma unroll
    for (int e = 0; e < 2; ++e) {
      const int rr = (tid >> 3) + e * 32;
      const int cc = (tid & 7) * 8;
      *(uint4*)&BsHi[rr][cc] =
          *(const uint4*)&WtHi[(size_t)(n0 + rr) * DMODEL + k0 + cc];
      *(uint4*)&BsLo[rr][cc] =
          *(const uint4*)&WtLo[(size_t)(n0 + rr) * DMODEL + k0 + cc];
    }
    __syncthreads();
    #pragma unroll
    for (int jt = 0; jt < 4; ++jt) {
      #pragma unroll
      for (int dc = 0; dc < 2; ++dc) {
        FragU bh, bl;
        bh.u = *(const uint4*)&BsHi[jt * 16 + lr][dc * 32 + lg * 8];
        bl.u = *(const uint4*)&BsLo[jt * 16 + lr][dc * 32 + lg * 8];
        acc[jt] = __builtin_amdgcn_mfma_f32_16x16x32_bf16(ah[dc].s, bh.s, acc[jt], 0, 0, 0);
        acc[jt] = __builtin_amdgcn_mfma_f32_16x16x32_bf16(ah[dc].s, bl.s, acc[jt], 0, 0, 0);
        if (MODE != 3)
          acc[jt] = __builtin_amdgcn_mfma_f32_16x16x32_bf16(al[dc].s, bh.s, acc[jt], 0, 0, 0);
      }
    }
  }

  if (MODE == 3) {
    #pragma unroll
    for (int jt = 0; jt < 4; ++jt) {
      const int n = n0 + jt * 16 + lr;
      const float bi = bias[n];
      #pragma unroll
      for (int r = 0; r < 4; ++r)
        Yf[(size_t)(mw + lg * 4 + r) * DMODEL + n] = acc[jt][r] + bi;
    }
  } else {
    __syncthreads();
    #pragma unroll
    for (int jt = 0; jt < 4; ++jt) {
      const int n = jt * 16 + lr;
      const float bi = bias[n0 + n];
      #pragma unroll
      for (int r = 0; r < 4; ++r) {
        const float v = acc[jt][r] + bi;
        const int row = wv * 16 + lg * 4 + r;
        unsigned short hi = f32_to_bf16(v);
        BsHi[row][n] = hi;
        if (MODE == 1) BsLo[row][n] = f32_to_bf16(v - bf16_to_f32(hi));
      }
    }
    __syncthreads();
    #pragma unroll
    for (int p = 0; p < 2; ++p) {
      const int row = (tid >> 3) + p * 32;
      const int ch = (tid & 7) * 8;
      const size_t o = (size_t)(m0 + row) * DMODEL + n0 + ch;
      *(uint4*)&Yhi[o] = *(uint4*)&BsHi[row][ch];
      if (MODE == 1) *(uint4*)&Ylo[o] = *(uint4*)&BsLo[row][ch];
    }
  }
}

// ---------------------------------------------------------------------------
// V flat [4096][512] bf16 -> Vt[bh][d][s] bf16
// ---------------------------------------------------------------------------
__global__ __launch_bounds__(256) void vtrans_kernel(
    const unsigned short* __restrict__ V16, unsigned short* __restrict__ Vt) {
  __shared__ unsigned short t[64][72];
  const int tid = threadIdx.x;
  const int bh = blockIdx.y, b = bh >> 3, h = bh & 7;
  const int s0 = blockIdx.x * 64;
  #pragma unroll
  for (int e = 0; e < 2; ++e) {
    int c = tid + e * 256;
    int r = c >> 3, c8 = (c & 7) * 8;
    *(uint4*)&t[r][c8] =
        *(const uint4*)&V16[(size_t)(b * SEQ + s0 + r) * DMODEL + h * DK + c8];
  }
  __syncthreads();
  const int d = tid >> 2, sc0 = (tid & 3) * 16;
  #pragma unroll
  for (int e = 0; e < 16; ++e)
    Vt[((size_t)bh * DK + d) * SEQ + s0 + sc0 + e] = t[sc0 + e][d];
}

// ---------------------------------------------------------------------------
// ONE-PASS fused attention v4: 2 q-sets per block for 2x K reuse.
// Block = 1024 thr / 16 waves, 32 q-rows (2 sets of 16), 128 cols/wave.
// Each K fragment pair feeds 8 MFMAs (2 qsets x 4). No-max softmax; e stored
// as f16 pairs. Grid 1024 (XCD-swizzled): K L2 traffic halves vs v3.
// Phase 2 per qset: p = e*il -> attn store + wave pbuf -> PV MFMA (V frags
// L2-hot). Epilogue: two sequential 16-way ctx tree-reduces.
// MFMA maps (verified): A[lr][lg*8+j]; B[lg*8+j][lr]; D[lg*4+r][lr].
// ---------------------------------------------------------------------------
__global__ __launch_bounds__(1024, 1) void attn_fused_kernel(
    const unsigned short* __restrict__ Qhi, const unsigned short* __restrict__ Qlo,
    const unsigned short* __restrict__ Khi, const unsigned int* __restrict__ bits,
    const unsigned short* __restrict__ Vt, float* __restrict__ attn,
    unsigned short* __restrict__ ctx16) {
  __shared__ unsigned short pbuf[16][16 * 76];  // 38912 B (also ctx reduce buf)
  __shared__ float smred[16][32];               // 2 KB (l partials, 2 qsets)
  const int id = blockIdx.x;                    // 1024 blocks, XCD-swizzled
  const int xcd = id & 7, slot = id >> 3;       // slot 0..127
  const int bh = xcd + 8 * (slot & 1);
  const int qt = slot >> 1;                     // 0..63
  const int b = bh >> 3, h = bh & 7;
  const int tid = threadIdx.x, wv = tid >> 6, lane = tid & 63;
  const int lr = lane & 15, lg = lane >> 4;
  const int q0 = qt * 32;
  const int kw = wv * 128;  // wave's k-column base

  // Q frags for both qsets (A layout: q-row = q0 + qs*16 + lr), hi+lo
  FragU qh[2][2], ql[2][2];
  #pragma unroll
  for (int qs = 0; qs < 2; ++qs)
    #pragma unroll
    for (int dc = 0; dc < 2; ++dc) {
      const size_t qi =
          (size_t)(b * SEQ + q0 + qs * 16 + lr) * DMODEL + h * DK + dc * 32 + lg * 8;
      qh[qs][dc].u = *(const uint4*)&Qhi[qi];
      ql[qs][dc].u = *(const uint4*)&Qlo[qi];
    }

  // ---- phase 1: e = exp(s/8) (masked -> 0) -> f16 pairs; l accumulates ----
  const float C = 0.125f * 1.44269504089f;  // fold scale into exp2
  PkU epk[2][8][2];
  float ls[2][4] = {};
  #pragma unroll
  for (int t = 0; t < 8; ++t) {
    FragU kh[2];
    #pragma unroll
    for (int dc = 0; dc < 2; ++dc) {
      const size_t kidx =
          (size_t)(b * SEQ + kw + t * 16 + lr) * DMODEL + h * DK + dc * 32 + lg * 8;
      kh[dc].u = *(const uint4*)&Khi[kidx];
    }
    #pragma unroll
    for (int qs = 0; qs < 2; ++qs) {
      f32x4 sa = {};
      #pragma unroll
      for (int dc = 0; dc < 2; ++dc) {
        sa = __builtin_amdgcn_mfma_f32_16x16x32_bf16(qh[qs][dc].s, kh[dc].s, sa, 0, 0, 0);
        sa = __builtin_amdgcn_mfma_f32_16x16x32_bf16(ql[qs][dc].s, kh[dc].s, sa, 0, 0, 0);
      }
      float ev[4];
      #pragma unroll
      for (int r = 0; r < 4; ++r) {
        const int q = q0 + qs * 16 + lg * 4 + r;
        const unsigned int w = bits[((size_t)b * SEQ + q) * 64 + (kw >> 5) + (t >> 1)];
        const bool keep = (w >> (((t & 1) << 4) + lr)) & 1;
        const float e = keep ? exp2f(sa[r] * C) : 0.0f;
        ev[r] = e;
        ls[qs][r] += e;
      }
      epk[qs][t][0].h = __builtin_amdgcn_cvt_pkrtz(ev[0], ev[1]);
      epk[qs][t][1].h = __builtin_amdgcn_cvt_pkrtz(ev[2], ev[3]);
    }
  }

  // ---- l: shfl reduce over the 16-lane lr group, then cross-wave via LDS ----
  #pragma unroll
  for (int qs = 0; qs < 2; ++qs)
    #pragma unroll
    for (int r = 0; r < 4; ++r) {
      #pragma unroll
      for (int off = 1; off < 16; off <<= 1) ls[qs][r] += __shfl_xor(ls[qs][r], off);
      if (lr == 0) smred[wv][qs * 16 + lg * 4 + r] = ls[qs][r];
    }
  __syncthreads();
  float il[2][4];
  #pragma unroll
  for (int qs = 0; qs < 2; ++qs)
    #pragma unroll
    for (int r = 0; r < 4; ++r) {
      float l = 0.f;
      #pragma unroll
      for (int w2 = 0; w2 < 16; ++w2) l += smred[w2][qs * 16 + lg * 4 + r];
      il[qs][r] = 1.0f / l;
    }

  // ---- phase 2: per qset: p -> attn store + pbuf -> PV MFMA ----
  unsigned short* pb = pbuf[wv];
  f32x4 acc[2][4] = {};
  #pragma unroll
  for (int qs = 0; qs < 2; ++qs) {
    #pragma unroll
    for (int c = 0; c < 2; ++c) {
      #pragma unroll
      for (int tt = 0; tt < 4; ++tt) {
        const int t = c * 4 + tt;
        float pv4[4];
        pv4[0] = (float)epk[qs][t][0].h.x * il[qs][0];
        pv4[1] = (float)epk[qs][t][0].h.y * il[qs][1];
        pv4[2] = (float)epk[qs][t][1].h.x * il[qs][2];
        pv4[3] = (float)epk[qs][t][1].h.y * il[qs][3];
        #pragma unroll
        for (int r = 0; r < 4; ++r) {
          const int q = q0 + qs * 16 + lg * 4 + r;
          attn[((size_t)bh * SEQ + q) * SEQ + kw + t * 16 + lr] = pv4[r];
          pb[(lg * 4 + r) * 76 + tt * 16 + lr] = f32_to_bf16(pv4[r]);
        }
      }
      #pragma unroll
      for (int dc2 = 0; dc2 < 2; ++dc2) {
        FragU pa;
        pa.u = *(const uint4*)&pb[lr * 76 + dc2 * 32 + lg * 8];
        #pragma unroll
        for (int dt = 0; dt < 4; ++dt) {
          FragU bv;
          bv.u = *(const uint4*)&Vt[((size_t)bh * DK + dt * 16 + lr) * SEQ + kw +
                                    c * 64 + dc2 * 32 + lg * 8];
          acc[qs][dt] = __builtin_amdgcn_mfma_f32_16x16x32_bf16(pa.s, bv.s, acc[qs][dt], 0, 0, 0);
        }
      }
    }
  }

  // ---- per qset: 16-way ctx tree-reduce through pbuf ----
  float* red = (float*)&pbuf[0][0];
  #pragma unroll 1
  for (int qs = 0; qs < 2; ++qs) {
    #pragma unroll 1
    for (int ofs = 8; ofs > 0; ofs >>= 1) {
      __syncthreads();
      if (wv >= ofs && wv < 2 * ofs) {
        float* dst = red + (size_t)(wv - ofs) * 1024;
        #pragma unroll
        for (int dt = 0; dt < 4; ++dt) *(f32x4*)&dst[dt * 256 + lane * 4] = acc[qs][dt];
      }
      __syncthreads();
      if (wv < ofs) {
        const float* src = red + (size_t)wv * 1024;
        #pragma unroll
        for (int dt = 0; dt < 4; ++dt)
          acc[qs][dt] += *(const f32x4*)&src[dt * 256 + lane * 4];
      }
    }
    if (wv == 0) {
      #pragma unroll
      for (int dt = 0; dt < 4; ++dt)
        #pragma unroll
        for (int r = 0; r < 4; ++r) {
          const int q = q0 + qs * 16 + lg * 4 + r;
          ctx16[(size_t)(b * SEQ + q) * DMODEL + h * DK + dt * 16 + lr] =
              f32_to_bf16(acc[qs][dt][r]);
        }
    }
  }
}

// ---------------------------------------------------------------------------
extern "C" void kernel_launch(void* const* d_in, const int* in_sizes, int n_in,
                              void* d_out, int out_size, void* d_ws,
                              size_t ws_size, hipStream_t stream) {
  const float* q = (const float*)d_in[0];
  const float* k = (const float*)d_in[1];
  const float* v = (const float*)d_in[2];
  const int* mask = (const int*)d_in[3];
  const float* Wq = (const float*)d_in[4];
  const float* bq = (const float*)d_in[5];
  const float* Wk = (const float*)d_in[6];
  const float* bk = (const float*)d_in[7];
  const float* Wv = (const float*)d_in[8];
  const float* bv = (const float*)d_in[9];
  const float* Wo = (const float*)d_in[10];
  const float* bo = (const float*)d_in[11];

  float* out = (float*)d_out;
  float* attn = out + (size_t)BATCH * SEQ * DMODEL;

  char* w = (char*)d_ws;
  const size_t MB = 1u << 20;
  unsigned short* Qhi = (unsigned short*)(w + 0 * MB);     // flat [4096][512]
  unsigned short* Qlo = (unsigned short*)(w + 4 * MB);
  unsigned short* Khi = (unsigned short*)(w + 8 * MB);     // single bf16
  unsigned short* V16 = (unsigned short*)(w + 16 * MB);    // dead after vtrans
  unsigned short* Vt = (unsigned short*)(w + 20 * MB);     // [bh][d][s]
  unsigned int* bits = (unsigned int*)(w + 24 * MB);       // 1 MB
  unsigned short* WtHi = (unsigned short*)(w + 26 * MB + 256 * 1024);  // 512 KB
  unsigned short* WtLo = (unsigned short*)(w + 26 * MB + 768 * 1024);  // 512 KB
  unsigned short* ctx16 = (unsigned short*)(w + 16 * MB);  // overlays V16

  dim3 blk(256);
  pack_mask_kernel<<<dim3(BATCH * SEQ), blk, 0, stream>>>(mask, bits);

  wsplit_kernel<<<dim3(8, 8), blk, 0, stream>>>(Wq, WtHi, WtLo);
  proj_mfma_kernel<1><<<dim3(64, 8), blk, 0, stream>>>(q, nullptr, WtHi, WtLo, bq,
                                                       nullptr, Qhi, Qlo);
  wsplit_kernel<<<dim3(8, 8), blk, 0, stream>>>(Wk, WtHi, WtLo);
  proj_mfma_kernel<2><<<dim3(64, 8), blk, 0, stream>>>(k, nullptr, WtHi, WtLo, bk,
                                                       nullptr, Khi, nullptr);
  wsplit_kernel<<<dim3(8, 8), blk, 0, stream>>>(Wv, WtHi, WtLo);
  proj_mfma_kernel<2><<<dim3(64, 8), blk, 0, stream>>>(v, nullptr, WtHi, WtLo, bv,
                                                       nullptr, V16, nullptr);
  vtrans_kernel<<<dim3(32, BH), blk, 0, stream>>>(V16, Vt);

  attn_fused_kernel<<<dim3(1024), dim3(1024), 0, stream>>>(Qhi, Qlo, Khi, bits,
                                                           Vt, attn, ctx16);

  wsplit_kernel<<<dim3(8, 8), blk, 0, stream>>>(Wo, WtHi, WtLo);
  proj_mfma_kernel<3><<<dim3(64, 8), blk, 0, stream>>>(nullptr, ctx16, WtHi, WtLo, bo,
                                                       out, nullptr, nullptr);
}

// Round 15
// 349.764 us; speedup vs baseline: 1.0015x; 1.0015x over previous
//
#include <hip/hip_runtime.h>
#include <math.h>

#define HEADS 8
#define DK 64
#define DMODEL 512
#define BATCH 2
#define SEQ 2048
#define BH (BATCH * HEADS)

using f32x4 = __attribute__((ext_vector_type(4))) float;
using s16x8 = __attribute__((ext_vector_type(8))) short;
using fp16x2 = __attribute__((ext_vector_type(2))) __fp16;  // cvt_pkrtz's type

union FragU {
  uint4 u;
  s16x8 s;
  unsigned short us[8];
};
union PkU {
  fp16x2 h;
  unsigned int u;
};

__device__ __forceinline__ unsigned short f32_to_bf16(float f) {
  unsigned int u = __float_as_uint(f);
  u += 0x7fffu + ((u >> 16) & 1u);
  return (unsigned short)(u >> 16);
}
__device__ __forceinline__ float bf16_to_f32(unsigned short h) {
  return __uint_as_float(((unsigned int)h) << 16);
}

// ---------------------------------------------------------------------------
// mask int32 [B][S][S] -> packed bits [B][S][S/32]. One block per row.
// ---------------------------------------------------------------------------
__global__ __launch_bounds__(256) void pack_mask_kernel(
    const int* __restrict__ mask, unsigned int* __restrict__ bits) {
  const size_t row = blockIdx.x;  // B*S = 4096 rows
  const int wv = threadIdx.x >> 6, lane = threadIdx.x & 63;
  #pragma unroll
  for (int i = 0; i < 8; ++i) {
    const int c = wv * 512 + i * 64 + lane;
    unsigned long long bal = __ballot(mask[row * SEQ + c] != 0);
    if (lane == 0) {
      bits[row * 64 + (c >> 5)] = (unsigned int)bal;
      bits[row * 64 + (c >> 5) + 1] = (unsigned int)(bal >> 32);
    }
  }
}

// ---------------------------------------------------------------------------
// W[512][512] f32 -> Wt hi/lo bf16 in [n][k] (transposed) layout.
// ---------------------------------------------------------------------------
__global__ __launch_bounds__(256) void wsplit_kernel(
    const float* __restrict__ W, unsigned short* __restrict__ WtHi,
    unsigned short* __restrict__ WtLo) {
  __shared__ float t[64][65];
  const int k0 = blockIdx.x * 64, n0 = blockIdx.y * 64;
  const int tid = threadIdx.x;
  const int r = tid >> 2, c = (tid & 3) * 16;
  #pragma unroll
  for (int e = 0; e < 4; ++e) {
    f32x4 v = *(const f32x4*)&W[(size_t)(k0 + r) * DMODEL + n0 + c + e * 4];
    #pragma unroll
    for (int j = 0; j < 4; ++j) t[r][c + e * 4 + j] = v[j];
  }
  __syncthreads();
  const int rn = tid >> 2, ck = (tid & 3) * 16;
  #pragma unroll
  for (int half = 0; half < 2; ++half) {
    FragU hi, lo;
    #pragma unroll
    for (int e = 0; e < 8; ++e) {
      float x = t[ck + half * 8 + e][rn];
      unsigned short h = f32_to_bf16(x);
      hi.us[e] = h;
      lo.us[e] = f32_to_bf16(x - bf16_to_f32(h));
    }
    const size_t o = (size_t)(n0 + rn) * DMODEL + k0 + ck + half * 8;
    *(uint4*)&WtHi[o] = hi.u;
    *(uint4*)&WtLo[o] = lo.u;
  }
}

// ---------------------------------------------------------------------------
// MFMA projection GEMM (R8 structure): B-tile LDS-staged, coalesced
// transposed output. All Y layouts FLAT [4096][512].
// MODE 1: Y -> bf16 hi/lo pair; MODE 2: Y -> bf16; MODE 3: X bf16, Y f32.
// ---------------------------------------------------------------------------
template <int MODE>
__global__ __launch_bounds__(256) void proj_mfma_kernel(
    const float* __restrict__ X, const unsigned short* __restrict__ X16,
    const unsigned short* __restrict__ WtHi,
    const unsigned short* __restrict__ WtLo, const float* __restrict__ bias,
    float* __restrict__ Yf, unsigned short* __restrict__ Yhi,
    unsigned short* __restrict__ Ylo) {
  __shared__ unsigned short BsHi[64][72];
  __shared__ unsigned short BsLo[64][72];
  const int tid = threadIdx.x, wv = tid >> 6, lane = tid & 63;
  const int lr = lane & 15, lg = lane >> 4;
  const int m0 = blockIdx.x * 64;
  const int mw = m0 + wv * 16;
  const int n0 = blockIdx.y * 64;

  f32x4 acc[4] = {};
  for (int k0 = 0; k0 < 512; k0 += 64) {
    FragU ah[2], al[2];
    #pragma unroll
    for (int dc = 0; dc < 2; ++dc) {
      const size_t xi = (size_t)(mw + lr) * DMODEL + k0 + dc * 32 + lg * 8;
      if (MODE == 3) {
        ah[dc].u = *(const uint4*)&X16[xi];
      } else {
        f32x4 x0 = *(const f32x4*)&X[xi];
        f32x4 x1 = *(const f32x4*)&X[xi + 4];
        #pragma unroll
        for (int t = 0; t < 4; ++t) {
          unsigned short h0 = f32_to_bf16(x0[t]);
          unsigned short h1 = f32_to_bf16(x1[t]);
          ah[dc].us[t] = h0;
          ah[dc].us[4 + t] = h1;
          al[dc].us[t] = f32_to_bf16(x0[t] - bf16_to_f32(h0));
          al[dc].us[4 + t] = f32_to_bf16(x1[t] - bf16_to_f32(h1));
        }
      }
    }
    __syncthreads();
    #pragma unroll
    for (int e = 0; e < 2; ++e) {
      const int rr = (tid >> 3) + e * 32;
      const int cc = (tid & 7) * 8;
      *(uint4*)&BsHi[rr][cc] =
          *(const uint4*)&WtHi[(size_t)(n0 + rr) * DMODEL + k0 + cc];
      *(uint4*)&BsLo[rr][cc] =
          *(const uint4*)&WtLo[(size_t)(n0 + rr) * DMODEL + k0 + cc];
    }
    __syncthreads();
    #pragma unroll
    for (int jt = 0; jt < 4; ++jt) {
      #pragma unroll
      for (int dc = 0; dc < 2; ++dc) {
        FragU bh, bl;
        bh.u = *(const uint4*)&BsHi[jt * 16 + lr][dc * 32 + lg * 8];
        bl.u = *(const uint4*)&BsLo[jt * 16 + lr][dc * 32 + lg * 8];
        acc[jt] = __builtin_amdgcn_mfma_f32_16x16x32_bf16(ah[dc].s, bh.s, acc[jt], 0, 0, 0);
        acc[jt] = __builtin_amdgcn_mfma_f32_16x16x32_bf16(ah[dc].s, bl.s, acc[jt], 0, 0, 0);
        if (MODE != 3)
          acc[jt] = __builtin_amdgcn_mfma_f32_16x16x32_bf16(al[dc].s, bh.s, acc[jt], 0, 0, 0);
      }
    }
  }

  if (MODE == 3) {
    #pragma unroll
    for (int jt = 0; jt < 4; ++jt) {
      const int n = n0 + jt * 16 + lr;
      const float bi = bias[n];
      #pragma unroll
      for (int r = 0; r < 4; ++r)
        Yf[(size_t)(mw + lg * 4 + r) * DMODEL + n] = acc[jt][r] + bi;
    }
  } else {
    __syncthreads();
    #pragma unroll
    for (int jt = 0; jt < 4; ++jt) {
      const int n = jt * 16 + lr;
      const float bi = bias[n0 + n];
      #pragma unroll
      for (int r = 0; r < 4; ++r) {
        const float v = acc[jt][r] + bi;
        const int row = wv * 16 + lg * 4 + r;
        unsigned short hi = f32_to_bf16(v);
        BsHi[row][n] = hi;
        if (MODE == 1) BsLo[row][n] = f32_to_bf16(v - bf16_to_f32(hi));
      }
    }
    __syncthreads();
    #pragma unroll
    for (int p = 0; p < 2; ++p) {
      const int row = (tid >> 3) + p * 32;
      const int ch = (tid & 7) * 8;
      const size_t o = (size_t)(m0 + row) * DMODEL + n0 + ch;
      *(uint4*)&Yhi[o] = *(uint4*)&BsHi[row][ch];
      if (MODE == 1) *(uint4*)&Ylo[o] = *(uint4*)&BsLo[row][ch];
    }
  }
}

// ---------------------------------------------------------------------------
// V flat [4096][512] bf16 -> Vt[bh][d][s] bf16
// ---------------------------------------------------------------------------
__global__ __launch_bounds__(256) void vtrans_kernel(
    const unsigned short* __restrict__ V16, unsigned short* __restrict__ Vt) {
  __shared__ unsigned short t[64][72];
  const int tid = threadIdx.x;
  const int bh = blockIdx.y, b = bh >> 3, h = bh & 7;
  const int s0 = blockIdx.x * 64;
  #pragma unroll
  for (int e = 0; e < 2; ++e) {
    int c = tid + e * 256;
    int r = c >> 3, c8 = (c & 7) * 8;
    *(uint4*)&t[r][c8] =
        *(const uint4*)&V16[(size_t)(b * SEQ + s0 + r) * DMODEL + h * DK + c8];
  }
  __syncthreads();
  const int d = tid >> 2, sc0 = (tid & 3) * 16;
  #pragma unroll
  for (int e = 0; e < 16; ++e)
    Vt[((size_t)bh * DK + d) * SEQ + s0 + sc0 + e] = t[sc0 + e][d];
}

// ---------------------------------------------------------------------------
// ONE-PASS fused attention v4b: 2 q-sets per block for 2x K reuse.
// Block = 1024 thr / 16 waves, 32 q-rows (2 sets of 16), 128 cols/wave.
// __launch_bounds__(1024, 4): a 16-wave block IS 4 waves/EU -> VGPR cap 128;
// R14's (1024,1) was unsatisfiable and caused a 64-VGPR alloc + ~580 MB of
// scratch spill traffic (WRITE_SIZE 266->722 MB). State fits ~110 VGPR.
// Each K fragment pair feeds 8 MFMAs (2 qsets x 4); K L2 traffic halves vs v3.
// MFMA maps (verified): A[lr][lg*8+j]; B[lg*8+j][lr]; D[lg*4+r][lr].
// ---------------------------------------------------------------------------
__global__ __launch_bounds__(1024, 4) void attn_fused_kernel(
    const unsigned short* __restrict__ Qhi, const unsigned short* __restrict__ Qlo,
    const unsigned short* __restrict__ Khi, const unsigned int* __restrict__ bits,
    const unsigned short* __restrict__ Vt, float* __restrict__ attn,
    unsigned short* __restrict__ ctx16) {
  __shared__ unsigned short pbuf[16][16 * 76];  // 38912 B (also ctx reduce buf)
  __shared__ float smred[16][32];               // 2 KB (l partials, 2 qsets)
  const int id = blockIdx.x;                    // 1024 blocks, XCD-swizzled
  const int xcd = id & 7, slot = id >> 3;       // slot 0..127
  const int bh = xcd + 8 * (slot & 1);
  const int qt = slot >> 1;                     // 0..63
  const int b = bh >> 3, h = bh & 7;
  const int tid = threadIdx.x, wv = tid >> 6, lane = tid & 63;
  const int lr = lane & 15, lg = lane >> 4;
  const int q0 = qt * 32;
  const int kw = wv * 128;  // wave's k-column base

  // Q frags for both qsets (A layout: q-row = q0 + qs*16 + lr), hi+lo
  FragU qh[2][2], ql[2][2];
  #pragma unroll
  for (int qs = 0; qs < 2; ++qs)
    #pragma unroll
    for (int dc = 0; dc < 2; ++dc) {
      const size_t qi =
          (size_t)(b * SEQ + q0 + qs * 16 + lr) * DMODEL + h * DK + dc * 32 + lg * 8;
      qh[qs][dc].u = *(const uint4*)&Qhi[qi];
      ql[qs][dc].u = *(const uint4*)&Qlo[qi];
    }

  // ---- phase 1: e = exp(s/8) (masked -> 0) -> f16 pairs; l accumulates ----
  const float C = 0.125f * 1.44269504089f;  // fold scale into exp2
  PkU epk[2][8][2];
  float ls[2][4] = {};
  #pragma unroll
  for (int t = 0; t < 8; ++t) {
    FragU kh[2];
    #pragma unroll
    for (int dc = 0; dc < 2; ++dc) {
      const size_t kidx =
          (size_t)(b * SEQ + kw + t * 16 + lr) * DMODEL + h * DK + dc * 32 + lg * 8;
      kh[dc].u = *(const uint4*)&Khi[kidx];
    }
    #pragma unroll
    for (int qs = 0; qs < 2; ++qs) {
      f32x4 sa = {};
      #pragma unroll
      for (int dc = 0; dc < 2; ++dc) {
        sa = __builtin_amdgcn_mfma_f32_16x16x32_bf16(qh[qs][dc].s, kh[dc].s, sa, 0, 0, 0);
        sa = __builtin_amdgcn_mfma_f32_16x16x32_bf16(ql[qs][dc].s, kh[dc].s, sa, 0, 0, 0);
      }
      float ev[4];
      #pragma unroll
      for (int r = 0; r < 4; ++r) {
        const int q = q0 + qs * 16 + lg * 4 + r;
        const unsigned int w = bits[((size_t)b * SEQ + q) * 64 + (kw >> 5) + (t >> 1)];
        const bool keep = (w >> (((t & 1) << 4) + lr)) & 1;
        const float e = keep ? exp2f(sa[r] * C) : 0.0f;
        ev[r] = e;
        ls[qs][r] += e;
      }
      epk[qs][t][0].h = __builtin_amdgcn_cvt_pkrtz(ev[0], ev[1]);
      epk[qs][t][1].h = __builtin_amdgcn_cvt_pkrtz(ev[2], ev[3]);
    }
  }

  // ---- l: shfl reduce over the 16-lane lr group, then cross-wave via LDS ----
  #pragma unroll
  for (int qs = 0; qs < 2; ++qs)
    #pragma unroll
    for (int r = 0; r < 4; ++r) {
      #pragma unroll
      for (int off = 1; off < 16; off <<= 1) ls[qs][r] += __shfl_xor(ls[qs][r], off);
      if (lr == 0) smred[wv][qs * 16 + lg * 4 + r] = ls[qs][r];
    }
  __syncthreads();
  float il[2][4];
  #pragma unroll
  for (int qs = 0; qs < 2; ++qs)
    #pragma unroll
    for (int r = 0; r < 4; ++r) {
      float l = 0.f;
      #pragma unroll
      for (int w2 = 0; w2 < 16; ++w2) l += smred[w2][qs * 16 + lg * 4 + r];
      il[qs][r] = 1.0f / l;
    }

  // ---- phase 2: per qset: p -> attn store + pbuf -> PV MFMA ----
  unsigned short* pb = pbuf[wv];
  f32x4 acc[2][4] = {};
  #pragma unroll
  for (int qs = 0; qs < 2; ++qs) {
    #pragma unroll
    for (int c = 0; c < 2; ++c) {
      #pragma unroll
      for (int tt = 0; tt < 4; ++tt) {
        const int t = c * 4 + tt;
        float pv4[4];
        pv4[0] = (float)epk[qs][t][0].h.x * il[qs][0];
        pv4[1] = (float)epk[qs][t][0].h.y * il[qs][1];
        pv4[2] = (float)epk[qs][t][1].h.x * il[qs][2];
        pv4[3] = (float)epk[qs][t][1].h.y * il[qs][3];
        #pragma unroll
        for (int r = 0; r < 4; ++r) {
          const int q = q0 + qs * 16 + lg * 4 + r;
          attn[((size_t)bh * SEQ + q) * SEQ + kw + t * 16 + lr] = pv4[r];
          pb[(lg * 4 + r) * 76 + tt * 16 + lr] = f32_to_bf16(pv4[r]);
        }
      }
      #pragma unroll
      for (int dc2 = 0; dc2 < 2; ++dc2) {
        FragU pa;
        pa.u = *(const uint4*)&pb[lr * 76 + dc2 * 32 + lg * 8];
        #pragma unroll
        for (int dt = 0; dt < 4; ++dt) {
          FragU bv;
          bv.u = *(const uint4*)&Vt[((size_t)bh * DK + dt * 16 + lr) * SEQ + kw +
                                    c * 64 + dc2 * 32 + lg * 8];
          acc[qs][dt] = __builtin_amdgcn_mfma_f32_16x16x32_bf16(pa.s, bv.s, acc[qs][dt], 0, 0, 0);
        }
      }
    }
  }

  // ---- per qset: 16-way ctx tree-reduce through pbuf ----
  float* red = (float*)&pbuf[0][0];
  #pragma unroll 1
  for (int qs = 0; qs < 2; ++qs) {
    #pragma unroll 1
    for (int ofs = 8; ofs > 0; ofs >>= 1) {
      __syncthreads();
      if (wv >= ofs && wv < 2 * ofs) {
        float* dst = red + (size_t)(wv - ofs) * 1024;
        #pragma unroll
        for (int dt = 0; dt < 4; ++dt) *(f32x4*)&dst[dt * 256 + lane * 4] = acc[qs][dt];
      }
      __syncthreads();
      if (wv < ofs) {
        const float* src = red + (size_t)wv * 1024;
        #pragma unroll
        for (int dt = 0; dt < 4; ++dt)
          acc[qs][dt] += *(const f32x4*)&src[dt * 256 + lane * 4];
      }
    }
    if (wv == 0) {
      #pragma unroll
      for (int dt = 0; dt < 4; ++dt)
        #pragma unroll
        for (int r = 0; r < 4; ++r) {
          const int q = q0 + qs * 16 + lg * 4 + r;
          ctx16[(size_t)(b * SEQ + q) * DMODEL + h * DK + dt * 16 + lr] =
              f32_to_bf16(acc[qs][dt][r]);
        }
    }
  }
}

// ---------------------------------------------------------------------------
extern "C" void kernel_launch(void* const* d_in, const int* in_sizes, int n_in,
                              void* d_out, int out_size, void* d_ws,
                              size_t ws_size, hipStream_t stream) {
  const float* q = (const float*)d_in[0];
  const float* k = (const float*)d_in[1];
  const float* v = (const float*)d_in[2];
  const int* mask = (const int*)d_in[3];
  const float* Wq = (const float*)d_in[4];
  const float* bq = (const float*)d_in[5];
  const float* Wk = (const float*)d_in[6];
  const float* bk = (const float*)d_in[7];
  const float* Wv = (const float*)d_in[8];
  const float* bv = (const float*)d_in[9];
  const float* Wo = (const float*)d_in[10];
  const float* bo = (const float*)d_in[11];

  float* out = (float*)d_out;
  float* attn = out + (size_t)BATCH * SEQ * DMODEL;

  char* w = (char*)d_ws;
  const size_t MB = 1u << 20;
  unsigned short* Qhi = (unsigned short*)(w + 0 * MB);     // flat [4096][512]
  unsigned short* Qlo = (unsigned short*)(w + 4 * MB);
  unsigned short* Khi = (unsigned short*)(w + 8 * MB);     // single bf16
  unsigned short* V16 = (unsigned short*)(w + 16 * MB);    // dead after vtrans
  unsigned short* Vt = (unsigned short*)(w + 20 * MB);     // [bh][d][s]
  unsigned int* bits = (unsigned int*)(w + 24 * MB);       // 1 MB
  unsigned short* WtHi = (unsigned short*)(w + 26 * MB + 256 * 1024);  // 512 KB
  unsigned short* WtLo = (unsigned short*)(w + 26 * MB + 768 * 1024);  // 512 KB
  unsigned short* ctx16 = (unsigned short*)(w + 16 * MB);  // overlays V16

  dim3 blk(256);
  pack_mask_kernel<<<dim3(BATCH * SEQ), blk, 0, stream>>>(mask, bits);

  wsplit_kernel<<<dim3(8, 8), blk, 0, stream>>>(Wq, WtHi, WtLo);
  proj_mfma_kernel<1><<<dim3(64, 8), blk, 0, stream>>>(q, nullptr, WtHi, WtLo, bq,
                                                       nullptr, Qhi, Qlo);
  wsplit_kernel<<<dim3(8, 8), blk, 0, stream>>>(Wk, WtHi, WtLo);
  proj_mfma_kernel<2><<<dim3(64, 8), blk, 0, stream>>>(k, nullptr, WtHi, WtLo, bk,
                                                       nullptr, Khi, nullptr);
  wsplit_kernel<<<dim3(8, 8), blk, 0, stream>>>(Wv, WtHi, WtLo);
  proj_mfma_kernel<2><<<dim3(64, 8), blk, 0, stream>>>(v, nullptr, WtHi, WtLo, bv,
                                                       nullptr, V16, nullptr);
  vtrans_kernel<<<dim3(32, BH), blk, 0, stream>>>(V16, Vt);

  attn_fused_kernel<<<dim3(1024), dim3(1024), 0, stream>>>(Qhi, Qlo, Khi, bits,
                                                           Vt, attn, ctx16);

  wsplit_kernel<<<dim3(8, 8), blk, 0, stream>>>(Wo, WtHi, WtLo);
  proj_mfma_kernel<3><<<dim3(64, 8), blk, 0, stream>>>(nullptr, ctx16, WtHi, WtLo, bo,
                                                       out, nullptr, nullptr);
}

// Round 16
// 317.845 us; speedup vs baseline: 1.1021x; 1.1004x over previous
//
#include <hip/hip_runtime.h>
#include <math.h>

#define HEADS 8
#define DK 64
#define DMODEL 512
#define BATCH 2
#define SEQ 2048
#define BH (BATCH * HEADS)

using f32x4 = __attribute__((ext_vector_type(4))) float;
using s16x8 = __attribute__((ext_vector_type(8))) short;
using fp16x2 = __attribute__((ext_vector_type(2))) __fp16;  // cvt_pkrtz's type

union FragU {
  uint4 u;
  s16x8 s;
  unsigned short us[8];
};
union PkU {
  fp16x2 h;
  unsigned int u;
};

__device__ __forceinline__ unsigned short f32_to_bf16(float f) {
  unsigned int u = __float_as_uint(f);
  u += 0x7fffu + ((u >> 16) & 1u);
  return (unsigned short)(u >> 16);
}
__device__ __forceinline__ float bf16_to_f32(unsigned short h) {
  return __uint_as_float(((unsigned int)h) << 16);
}

// ---------------------------------------------------------------------------
// mask int32 [B][S][S] -> packed bits [B][S][S/32]. One block per row.
// ---------------------------------------------------------------------------
__global__ __launch_bounds__(256) void pack_mask_kernel(
    const int* __restrict__ mask, unsigned int* __restrict__ bits) {
  const size_t row = blockIdx.x;  // B*S = 4096 rows
  const int wv = threadIdx.x >> 6, lane = threadIdx.x & 63;
  #pragma unroll
  for (int i = 0; i < 8; ++i) {
    const int c = wv * 512 + i * 64 + lane;
    unsigned long long bal = __ballot(mask[row * SEQ + c] != 0);
    if (lane == 0) {
      bits[row * 64 + (c >> 5)] = (unsigned int)bal;
      bits[row * 64 + (c >> 5) + 1] = (unsigned int)(bal >> 32);
    }
  }
}

// ---------------------------------------------------------------------------
// W[512][512] f32 -> Wt hi/lo bf16 in [n][k] (transposed) layout.
// ---------------------------------------------------------------------------
__global__ __launch_bounds__(256) void wsplit_kernel(
    const float* __restrict__ W, unsigned short* __restrict__ WtHi,
    unsigned short* __restrict__ WtLo) {
  __shared__ float t[64][65];
  const int k0 = blockIdx.x * 64, n0 = blockIdx.y * 64;
  const int tid = threadIdx.x;
  const int r = tid >> 2, c = (tid & 3) * 16;
  #pragma unroll
  for (int e = 0; e < 4; ++e) {
    f32x4 v = *(const f32x4*)&W[(size_t)(k0 + r) * DMODEL + n0 + c + e * 4];
    #pragma unroll
    for (int j = 0; j < 4; ++j) t[r][c + e * 4 + j] = v[j];
  }
  __syncthreads();
  const int rn = tid >> 2, ck = (tid & 3) * 16;
  #pragma unroll
  for (int half = 0; half < 2; ++half) {
    FragU hi, lo;
    #pragma unroll
    for (int e = 0; e < 8; ++e) {
      float x = t[ck + half * 8 + e][rn];
      unsigned short h = f32_to_bf16(x);
      hi.us[e] = h;
      lo.us[e] = f32_to_bf16(x - bf16_to_f32(h));
    }
    const size_t o = (size_t)(n0 + rn) * DMODEL + k0 + ck + half * 8;
    *(uint4*)&WtHi[o] = hi.u;
    *(uint4*)&WtLo[o] = lo.u;
  }
}

// ---------------------------------------------------------------------------
// MFMA projection GEMM (R8 structure): B-tile LDS-staged, coalesced
// transposed output. All Y layouts FLAT [4096][512].
// MODE 1: Y -> bf16 hi/lo pair; MODE 2: Y -> bf16; MODE 3: X bf16, Y f32.
// ---------------------------------------------------------------------------
template <int MODE>
__global__ __launch_bounds__(256) void proj_mfma_kernel(
    const float* __restrict__ X, const unsigned short* __restrict__ X16,
    const unsigned short* __restrict__ WtHi,
    const unsigned short* __restrict__ WtLo, const float* __restrict__ bias,
    float* __restrict__ Yf, unsigned short* __restrict__ Yhi,
    unsigned short* __restrict__ Ylo) {
  __shared__ unsigned short BsHi[64][72];
  __shared__ unsigned short BsLo[64][72];
  const int tid = threadIdx.x, wv = tid >> 6, lane = tid & 63;
  const int lr = lane & 15, lg = lane >> 4;
  const int m0 = blockIdx.x * 64;
  const int mw = m0 + wv * 16;
  const int n0 = blockIdx.y * 64;

  f32x4 acc[4] = {};
  for (int k0 = 0; k0 < 512; k0 += 64) {
    FragU ah[2], al[2];
    #pragma unroll
    for (int dc = 0; dc < 2; ++dc) {
      const size_t xi = (size_t)(mw + lr) * DMODEL + k0 + dc * 32 + lg * 8;
      if (MODE == 3) {
        ah[dc].u = *(const uint4*)&X16[xi];
      } else {
        f32x4 x0 = *(const f32x4*)&X[xi];
        f32x4 x1 = *(const f32x4*)&X[xi + 4];
        #pragma unroll
        for (int t = 0; t < 4; ++t) {
          unsigned short h0 = f32_to_bf16(x0[t]);
          unsigned short h1 = f32_to_bf16(x1[t]);
          ah[dc].us[t] = h0;
          ah[dc].us[4 + t] = h1;
          al[dc].us[t] = f32_to_bf16(x0[t] - bf16_to_f32(h0));
          al[dc].us[4 + t] = f32_to_bf16(x1[t] - bf16_to_f32(h1));
        }
      }
    }
    __syncthreads();
    #pragma unroll
    for (int e = 0; e < 2; ++e) {
      const int rr = (tid >> 3) + e * 32;
      const int cc = (tid & 7) * 8;
      *(uint4*)&BsHi[rr][cc] =
          *(const uint4*)&WtHi[(size_t)(n0 + rr) * DMODEL + k0 + cc];
      *(uint4*)&BsLo[rr][cc] =
          *(const uint4*)&WtLo[(size_t)(n0 + rr) * DMODEL + k0 + cc];
    }
    __syncthreads();
    #pragma unroll
    for (int jt = 0; jt < 4; ++jt) {
      #pragma unroll
      for (int dc = 0; dc < 2; ++dc) {
        FragU bh, bl;
        bh.u = *(const uint4*)&BsHi[jt * 16 + lr][dc * 32 + lg * 8];
        bl.u = *(const uint4*)&BsLo[jt * 16 + lr][dc * 32 + lg * 8];
        acc[jt] = __builtin_amdgcn_mfma_f32_16x16x32_bf16(ah[dc].s, bh.s, acc[jt], 0, 0, 0);
        acc[jt] = __builtin_amdgcn_mfma_f32_16x16x32_bf16(ah[dc].s, bl.s, acc[jt], 0, 0, 0);
        if (MODE != 3)
          acc[jt] = __builtin_amdgcn_mfma_f32_16x16x32_bf16(al[dc].s, bh.s, acc[jt], 0, 0, 0);
      }
    }
  }

  if (MODE == 3) {
    #pragma unroll
    for (int jt = 0; jt < 4; ++jt) {
      const int n = n0 + jt * 16 + lr;
      const float bi = bias[n];
      #pragma unroll
      for (int r = 0; r < 4; ++r)
        Yf[(size_t)(mw + lg * 4 + r) * DMODEL + n] = acc[jt][r] + bi;
    }
  } else {
    __syncthreads();
    #pragma unroll
    for (int jt = 0; jt < 4; ++jt) {
      const int n = jt * 16 + lr;
      const float bi = bias[n0 + n];
      #pragma unroll
      for (int r = 0; r < 4; ++r) {
        const float v = acc[jt][r] + bi;
        const int row = wv * 16 + lg * 4 + r;
        unsigned short hi = f32_to_bf16(v);
        BsHi[row][n] = hi;
        if (MODE == 1) BsLo[row][n] = f32_to_bf16(v - bf16_to_f32(hi));
      }
    }
    __syncthreads();
    #pragma unroll
    for (int p = 0; p < 2; ++p) {
      const int row = (tid >> 3) + p * 32;
      const int ch = (tid & 7) * 8;
      const size_t o = (size_t)(m0 + row) * DMODEL + n0 + ch;
      *(uint4*)&Yhi[o] = *(uint4*)&BsHi[row][ch];
      if (MODE == 1) *(uint4*)&Ylo[o] = *(uint4*)&BsLo[row][ch];
    }
  }
}

// ---------------------------------------------------------------------------
// V flat [4096][512] bf16 -> Vt[bh][d][s] bf16
// ---------------------------------------------------------------------------
__global__ __launch_bounds__(256) void vtrans_kernel(
    const unsigned short* __restrict__ V16, unsigned short* __restrict__ Vt) {
  __shared__ unsigned short t[64][72];
  const int tid = threadIdx.x;
  const int bh = blockIdx.y, b = bh >> 3, h = bh & 7;
  const int s0 = blockIdx.x * 64;
  #pragma unroll
  for (int e = 0; e < 2; ++e) {
    int c = tid + e * 256;
    int r = c >> 3, c8 = (c & 7) * 8;
    *(uint4*)&t[r][c8] =
        *(const uint4*)&V16[(size_t)(b * SEQ + s0 + r) * DMODEL + h * DK + c8];
  }
  __syncthreads();
  const int d = tid >> 2, sc0 = (tid & 3) * 16;
  #pragma unroll
  for (int e = 0; e < 16; ++e)
    Vt[((size_t)bh * DK + d) * SEQ + s0 + sc0 + e] = t[sc0 + e][d];
}

// ---------------------------------------------------------------------------
// ONE-PASS fused attention v5: 2 q-sets, 512-thread block (register file
// actually available here: R10/R11 512-thr builds allocated 72-88 VGPR with
// no spill; both 1024-thr attempts were force-capped at 64 VGPR + spill).
// Block = 8 waves, 32 q-rows (2 sets of 16); wave owns a 256-col stripe
// (16 t-steps). Each K fragment pair feeds 8 MFMAs (2 qsets x 4): K L2
// traffic halves vs R13. No-max softmax; e as f16 pairs (epk: 64 VGPR).
// Phase 2 per qset: p -> attn store + wave pbuf -> PV MFMA. Epilogue: two
// sequential 8-way ctx tree-reduces.
// MFMA maps (verified): A[lr][lg*8+j]; B[lg*8+j][lr]; D[lg*4+r][lr].
// ---------------------------------------------------------------------------
__global__ __launch_bounds__(512) void attn_fused_kernel(
    const unsigned short* __restrict__ Qhi, const unsigned short* __restrict__ Qlo,
    const unsigned short* __restrict__ Khi, const unsigned int* __restrict__ bits,
    const unsigned short* __restrict__ Vt, float* __restrict__ attn,
    unsigned short* __restrict__ ctx16) {
  __shared__ unsigned short pbuf[8][16 * 76];  // 19456 B (also ctx reduce buf)
  __shared__ float smred[8][32];               // 1 KB (l partials, 2 qsets)
  const int id = blockIdx.x;                   // 1024 blocks, XCD-swizzled
  const int xcd = id & 7, slot = id >> 3;      // slot 0..127
  const int bh = xcd + 8 * (slot & 1);
  const int qt = slot >> 1;                    // 0..63
  const int b = bh >> 3, h = bh & 7;
  const int tid = threadIdx.x, wv = tid >> 6, lane = tid & 63;
  const int lr = lane & 15, lg = lane >> 4;
  const int q0 = qt * 32;
  const int kw = wv * 256;  // wave's k-column base

  // Q frags for both qsets (A layout: q-row = q0 + qs*16 + lr), hi+lo
  FragU qh[2][2], ql[2][2];
  #pragma unroll
  for (int qs = 0; qs < 2; ++qs)
    #pragma unroll
    for (int dc = 0; dc < 2; ++dc) {
      const size_t qi =
          (size_t)(b * SEQ + q0 + qs * 16 + lr) * DMODEL + h * DK + dc * 32 + lg * 8;
      qh[qs][dc].u = *(const uint4*)&Qhi[qi];
      ql[qs][dc].u = *(const uint4*)&Qlo[qi];
    }

  // ---- phase 1: e = exp(s/8) (masked -> 0) -> f16 pairs; l accumulates ----
  const float C = 0.125f * 1.44269504089f;  // fold scale into exp2
  PkU epk[2][16][2];
  float ls[2][4] = {};
  #pragma unroll
  for (int t = 0; t < 16; ++t) {
    FragU kh[2];
    #pragma unroll
    for (int dc = 0; dc < 2; ++dc) {
      const size_t kidx =
          (size_t)(b * SEQ + kw + t * 16 + lr) * DMODEL + h * DK + dc * 32 + lg * 8;
      kh[dc].u = *(const uint4*)&Khi[kidx];
    }
    #pragma unroll
    for (int qs = 0; qs < 2; ++qs) {
      f32x4 sa = {};
      #pragma unroll
      for (int dc = 0; dc < 2; ++dc) {
        sa = __builtin_amdgcn_mfma_f32_16x16x32_bf16(qh[qs][dc].s, kh[dc].s, sa, 0, 0, 0);
        sa = __builtin_amdgcn_mfma_f32_16x16x32_bf16(ql[qs][dc].s, kh[dc].s, sa, 0, 0, 0);
      }
      float ev[4];
      #pragma unroll
      for (int r = 0; r < 4; ++r) {
        const int q = q0 + qs * 16 + lg * 4 + r;
        const unsigned int w = bits[((size_t)b * SEQ + q) * 64 + (kw >> 5) + (t >> 1)];
        const bool keep = (w >> (((t & 1) << 4) + lr)) & 1;
        const float e = keep ? exp2f(sa[r] * C) : 0.0f;
        ev[r] = e;
        ls[qs][r] += e;
      }
      epk[qs][t][0].h = __builtin_amdgcn_cvt_pkrtz(ev[0], ev[1]);
      epk[qs][t][1].h = __builtin_amdgcn_cvt_pkrtz(ev[2], ev[3]);
    }
  }

  // ---- l: shfl reduce over the 16-lane lr group, then cross-wave via LDS ----
  #pragma unroll
  for (int qs = 0; qs < 2; ++qs)
    #pragma unroll
    for (int r = 0; r < 4; ++r) {
      #pragma unroll
      for (int off = 1; off < 16; off <<= 1) ls[qs][r] += __shfl_xor(ls[qs][r], off);
      if (lr == 0) smred[wv][qs * 16 + lg * 4 + r] = ls[qs][r];
    }
  __syncthreads();
  float il[2][4];
  #pragma unroll
  for (int qs = 0; qs < 2; ++qs)
    #pragma unroll
    for (int r = 0; r < 4; ++r) {
      float l = 0.f;
      #pragma unroll
      for (int w2 = 0; w2 < 8; ++w2) l += smred[w2][qs * 16 + lg * 4 + r];
      il[qs][r] = 1.0f / l;
    }

  // ---- phase 2: per qset: p -> attn store + pbuf -> PV MFMA ----
  unsigned short* pb = pbuf[wv];
  f32x4 acc[2][4] = {};
  #pragma unroll
  for (int qs = 0; qs < 2; ++qs) {
    #pragma unroll
    for (int c = 0; c < 4; ++c) {
      #pragma unroll
      for (int tt = 0; tt < 4; ++tt) {
        const int t = c * 4 + tt;
        float pv4[4];
        pv4[0] = (float)epk[qs][t][0].h.x * il[qs][0];
        pv4[1] = (float)epk[qs][t][0].h.y * il[qs][1];
        pv4[2] = (float)epk[qs][t][1].h.x * il[qs][2];
        pv4[3] = (float)epk[qs][t][1].h.y * il[qs][3];
        #pragma unroll
        for (int r = 0; r < 4; ++r) {
          const int q = q0 + qs * 16 + lg * 4 + r;
          attn[((size_t)bh * SEQ + q) * SEQ + kw + t * 16 + lr] = pv4[r];
          pb[(lg * 4 + r) * 76 + tt * 16 + lr] = f32_to_bf16(pv4[r]);
        }
      }
      #pragma unroll
      for (int dc2 = 0; dc2 < 2; ++dc2) {
        FragU pa;
        pa.u = *(const uint4*)&pb[lr * 76 + dc2 * 32 + lg * 8];
        #pragma unroll
        for (int dt = 0; dt < 4; ++dt) {
          FragU bv;
          bv.u = *(const uint4*)&Vt[((size_t)bh * DK + dt * 16 + lr) * SEQ + kw +
                                    c * 64 + dc2 * 32 + lg * 8];
          acc[qs][dt] = __builtin_amdgcn_mfma_f32_16x16x32_bf16(pa.s, bv.s, acc[qs][dt], 0, 0, 0);
        }
      }
    }
  }

  // ---- per qset: 8-way ctx tree-reduce through pbuf (16 KB max in flight) --
  float* red = (float*)&pbuf[0][0];
  #pragma unroll 1
  for (int qs = 0; qs < 2; ++qs) {
    #pragma unroll 1
    for (int ofs = 4; ofs > 0; ofs >>= 1) {
      __syncthreads();
      if (wv >= ofs && wv < 2 * ofs) {
        float* dst = red + (size_t)(wv - ofs) * 1024;
        #pragma unroll
        for (int dt = 0; dt < 4; ++dt) *(f32x4*)&dst[dt * 256 + lane * 4] = acc[qs][dt];
      }
      __syncthreads();
      if (wv < ofs) {
        const float* src = red + (size_t)wv * 1024;
        #pragma unroll
        for (int dt = 0; dt < 4; ++dt)
          acc[qs][dt] += *(const f32x4*)&src[dt * 256 + lane * 4];
      }
    }
    if (wv == 0) {
      #pragma unroll
      for (int dt = 0; dt < 4; ++dt)
        #pragma unroll
        for (int r = 0; r < 4; ++r) {
          const int q = q0 + qs * 16 + lg * 4 + r;
          ctx16[(size_t)(b * SEQ + q) * DMODEL + h * DK + dt * 16 + lr] =
              f32_to_bf16(acc[qs][dt][r]);
        }
    }
  }
}

// ---------------------------------------------------------------------------
extern "C" void kernel_launch(void* const* d_in, const int* in_sizes, int n_in,
                              void* d_out, int out_size, void* d_ws,
                              size_t ws_size, hipStream_t stream) {
  const float* q = (const float*)d_in[0];
  const float* k = (const float*)d_in[1];
  const float* v = (const float*)d_in[2];
  const int* mask = (const int*)d_in[3];
  const float* Wq = (const float*)d_in[4];
  const float* bq = (const float*)d_in[5];
  const float* Wk = (const float*)d_in[6];
  const float* bk = (const float*)d_in[7];
  const float* Wv = (const float*)d_in[8];
  const float* bv = (const float*)d_in[9];
  const float* Wo = (const float*)d_in[10];
  const float* bo = (const float*)d_in[11];

  float* out = (float*)d_out;
  float* attn = out + (size_t)BATCH * SEQ * DMODEL;

  char* w = (char*)d_ws;
  const size_t MB = 1u << 20;
  unsigned short* Qhi = (unsigned short*)(w + 0 * MB);     // flat [4096][512]
  unsigned short* Qlo = (unsigned short*)(w + 4 * MB);
  unsigned short* Khi = (unsigned short*)(w + 8 * MB);     // single bf16
  unsigned short* V16 = (unsigned short*)(w + 16 * MB);    // dead after vtrans
  unsigned short* Vt = (unsigned short*)(w + 20 * MB);     // [bh][d][s]
  unsigned int* bits = (unsigned int*)(w + 24 * MB);       // 1 MB
  unsigned short* WtHi = (unsigned short*)(w + 26 * MB + 256 * 1024);  // 512 KB
  unsigned short* WtLo = (unsigned short*)(w + 26 * MB + 768 * 1024);  // 512 KB
  unsigned short* ctx16 = (unsigned short*)(w + 16 * MB);  // overlays V16

  dim3 blk(256);
  pack_mask_kernel<<<dim3(BATCH * SEQ), blk, 0, stream>>>(mask, bits);

  wsplit_kernel<<<dim3(8, 8), blk, 0, stream>>>(Wq, WtHi, WtLo);
  proj_mfma_kernel<1><<<dim3(64, 8), blk, 0, stream>>>(q, nullptr, WtHi, WtLo, bq,
                                                       nullptr, Qhi, Qlo);
  wsplit_kernel<<<dim3(8, 8), blk, 0, stream>>>(Wk, WtHi, WtLo);
  proj_mfma_kernel<2><<<dim3(64, 8), blk, 0, stream>>>(k, nullptr, WtHi, WtLo, bk,
                                                       nullptr, Khi, nullptr);
  wsplit_kernel<<<dim3(8, 8), blk, 0, stream>>>(Wv, WtHi, WtLo);
  proj_mfma_kernel<2><<<dim3(64, 8), blk, 0, stream>>>(v, nullptr, WtHi, WtLo, bv,
                                                       nullptr, V16, nullptr);
  vtrans_kernel<<<dim3(32, BH), blk, 0, stream>>>(V16, Vt);

  attn_fused_kernel<<<dim3(1024), dim3(512), 0, stream>>>(Qhi, Qlo, Khi, bits,
                                                          Vt, attn, ctx16);

  wsplit_kernel<<<dim3(8, 8), blk, 0, stream>>>(Wo, WtHi, WtLo);
  proj_mfma_kernel<3><<<dim3(64, 8), blk, 0, stream>>>(nullptr, ctx16, WtHi, WtLo, bo,
                                                       out, nullptr, nullptr);
}

// Round 17
// 262.925 us; speedup vs baseline: 1.3323x; 1.2089x over previous
//
#include <hip/hip_runtime.h>
#include <math.h>

#define HEADS 8
#define DK 64
#define DMODEL 512
#define BATCH 2
#define SEQ 2048
#define BH (BATCH * HEADS)

using f32x4 = __attribute__((ext_vector_type(4))) float;
using s16x8 = __attribute__((ext_vector_type(8))) short;
using fp16x2 = __attribute__((ext_vector_type(2))) __fp16;  // cvt_pkrtz's type

union FragU {
  uint4 u;
  s16x8 s;
  unsigned short us[8];
};
union PkU {
  fp16x2 h;
  unsigned int u;
};

__device__ __forceinline__ unsigned short f32_to_bf16(float f) {
  unsigned int u = __float_as_uint(f);
  u += 0x7fffu + ((u >> 16) & 1u);
  return (unsigned short)(u >> 16);
}
__device__ __forceinline__ float bf16_to_f32(unsigned short h) {
  return __uint_as_float(((unsigned int)h) << 16);
}

// ---------------------------------------------------------------------------
// mask int32 [B][S][S] -> packed bits [B][S][S/32]. One block per row.
// ---------------------------------------------------------------------------
__global__ __launch_bounds__(256) void pack_mask_kernel(
    const int* __restrict__ mask, unsigned int* __restrict__ bits) {
  const size_t row = blockIdx.x;  // B*S = 4096 rows
  const int wv = threadIdx.x >> 6, lane = threadIdx.x & 63;
  #pragma unroll
  for (int i = 0; i < 8; ++i) {
    const int c = wv * 512 + i * 64 + lane;
    unsigned long long bal = __ballot(mask[row * SEQ + c] != 0);
    if (lane == 0) {
      bits[row * 64 + (c >> 5)] = (unsigned int)bal;
      bits[row * 64 + (c >> 5) + 1] = (unsigned int)(bal >> 32);
    }
  }
}

// ---------------------------------------------------------------------------
// ALL FOUR W[512][512] f32 -> Wt hi/lo bf16 [n][k] in one launch.
// Grid (8,8,4); z selects the weight matrix; pair z lives at z*262144.
// ---------------------------------------------------------------------------
__global__ __launch_bounds__(256) void wsplit4_kernel(
    const float* __restrict__ W0, const float* __restrict__ W1,
    const float* __restrict__ W2, const float* __restrict__ W3,
    unsigned short* __restrict__ WtHi4, unsigned short* __restrict__ WtLo4) {
  __shared__ float t[64][65];
  const int z = blockIdx.z;
  const float* W = (z == 0) ? W0 : (z == 1) ? W1 : (z == 2) ? W2 : W3;
  unsigned short* WtHi = WtHi4 + (size_t)z * (DMODEL * DMODEL);
  unsigned short* WtLo = WtLo4 + (size_t)z * (DMODEL * DMODEL);
  const int k0 = blockIdx.x * 64, n0 = blockIdx.y * 64;
  const int tid = threadIdx.x;
  const int r = tid >> 2, c = (tid & 3) * 16;
  #pragma unroll
  for (int e = 0; e < 4; ++e) {
    f32x4 v = *(const f32x4*)&W[(size_t)(k0 + r) * DMODEL + n0 + c + e * 4];
    #pragma unroll
    for (int j = 0; j < 4; ++j) t[r][c + e * 4 + j] = v[j];
  }
  __syncthreads();
  const int rn = tid >> 2, ck = (tid & 3) * 16;
  #pragma unroll
  for (int half = 0; half < 2; ++half) {
    FragU hi, lo;
    #pragma unroll
    for (int e = 0; e < 8; ++e) {
      float x = t[ck + half * 8 + e][rn];
      unsigned short h = f32_to_bf16(x);
      hi.us[e] = h;
      lo.us[e] = f32_to_bf16(x - bf16_to_f32(h));
    }
    const size_t o = (size_t)(n0 + rn) * DMODEL + k0 + ck + half * 8;
    *(uint4*)&WtHi[o] = hi.u;
    *(uint4*)&WtLo[o] = lo.u;
  }
}

// ---------------------------------------------------------------------------
// MFMA projection GEMM (R8 structure): B-tile LDS-staged, coalesced
// transposed output. All Y layouts FLAT [4096][512].
// MODE 1: Y -> bf16 hi/lo pair; MODE 2: Y -> bf16; MODE 3: X bf16, Y f32.
// ---------------------------------------------------------------------------
template <int MODE>
__global__ __launch_bounds__(256) void proj_mfma_kernel(
    const float* __restrict__ X, const unsigned short* __restrict__ X16,
    const unsigned short* __restrict__ WtHi,
    const unsigned short* __restrict__ WtLo, const float* __restrict__ bias,
    float* __restrict__ Yf, unsigned short* __restrict__ Yhi,
    unsigned short* __restrict__ Ylo) {
  __shared__ unsigned short BsHi[64][72];
  __shared__ unsigned short BsLo[64][72];
  const int tid = threadIdx.x, wv = tid >> 6, lane = tid & 63;
  const int lr = lane & 15, lg = lane >> 4;
  const int m0 = blockIdx.x * 64;
  const int mw = m0 + wv * 16;
  const int n0 = blockIdx.y * 64;

  f32x4 acc[4] = {};
  for (int k0 = 0; k0 < 512; k0 += 64) {
    FragU ah[2], al[2];
    #pragma unroll
    for (int dc = 0; dc < 2; ++dc) {
      const size_t xi = (size_t)(mw + lr) * DMODEL + k0 + dc * 32 + lg * 8;
      if (MODE == 3) {
        ah[dc].u = *(const uint4*)&X16[xi];
      } else {
        f32x4 x0 = *(const f32x4*)&X[xi];
        f32x4 x1 = *(const f32x4*)&X[xi + 4];
        #pragma unroll
        for (int t = 0; t < 4; ++t) {
          unsigned short h0 = f32_to_bf16(x0[t]);
          unsigned short h1 = f32_to_bf16(x1[t]);
          ah[dc].us[t] = h0;
          ah[dc].us[4 + t] = h1;
          al[dc].us[t] = f32_to_bf16(x0[t] - bf16_to_f32(h0));
          al[dc].us[4 + t] = f32_to_bf16(x1[t] - bf16_to_f32(h1));
        }
      }
    }
    __syncthreads();
    #pragma unroll
    for (int e = 0; e < 2; ++e) {
      const int rr = (tid >> 3) + e * 32;
      const int cc = (tid & 7) * 8;
      *(uint4*)&BsHi[rr][cc] =
          *(const uint4*)&WtHi[(size_t)(n0 + rr) * DMODEL + k0 + cc];
      *(uint4*)&BsLo[rr][cc] =
          *(const uint4*)&WtLo[(size_t)(n0 + rr) * DMODEL + k0 + cc];
    }
    __syncthreads();
    #pragma unroll
    for (int jt = 0; jt < 4; ++jt) {
      #pragma unroll
      for (int dc = 0; dc < 2; ++dc) {
        FragU bh, bl;
        bh.u = *(const uint4*)&BsHi[jt * 16 + lr][dc * 32 + lg * 8];
        bl.u = *(const uint4*)&BsLo[jt * 16 + lr][dc * 32 + lg * 8];
        acc[jt] = __builtin_amdgcn_mfma_f32_16x16x32_bf16(ah[dc].s, bh.s, acc[jt], 0, 0, 0);
        acc[jt] = __builtin_amdgcn_mfma_f32_16x16x32_bf16(ah[dc].s, bl.s, acc[jt], 0, 0, 0);
        if (MODE != 3)
          acc[jt] = __builtin_amdgcn_mfma_f32_16x16x32_bf16(al[dc].s, bh.s, acc[jt], 0, 0, 0);
      }
    }
  }

  if (MODE == 3) {
    #pragma unroll
    for (int jt = 0; jt < 4; ++jt) {
      const int n = n0 + jt * 16 + lr;
      const float bi = bias[n];
      #pragma unroll
      for (int r = 0; r < 4; ++r)
        Yf[(size_t)(mw + lg * 4 + r) * DMODEL + n] = acc[jt][r] + bi;
    }
  } else {
    __syncthreads();
    #pragma unroll
    for (int jt = 0; jt < 4; ++jt) {
      const int n = jt * 16 + lr;
      const float bi = bias[n0 + n];
      #pragma unroll
      for (int r = 0; r < 4; ++r) {
        const float v = acc[jt][r] + bi;
        const int row = wv * 16 + lg * 4 + r;
        unsigned short hi = f32_to_bf16(v);
        BsHi[row][n] = hi;
        if (MODE == 1) BsLo[row][n] = f32_to_bf16(v - bf16_to_f32(hi));
      }
    }
    __syncthreads();
    #pragma unroll
    for (int p = 0; p < 2; ++p) {
      const int row = (tid >> 3) + p * 32;
      const int ch = (tid & 7) * 8;
      const size_t o = (size_t)(m0 + row) * DMODEL + n0 + ch;
      *(uint4*)&Yhi[o] = *(uint4*)&BsHi[row][ch];
      if (MODE == 1) *(uint4*)&Ylo[o] = *(uint4*)&BsLo[row][ch];
    }
  }
}

// ---------------------------------------------------------------------------
// V flat [4096][512] bf16 -> Vt[bh][d][s] bf16
// ---------------------------------------------------------------------------
__global__ __launch_bounds__(256) void vtrans_kernel(
    const unsigned short* __restrict__ V16, unsigned short* __restrict__ Vt) {
  __shared__ unsigned short t[64][72];
  const int tid = threadIdx.x;
  const int bh = blockIdx.y, b = bh >> 3, h = bh & 7;
  const int s0 = blockIdx.x * 64;
  #pragma unroll
  for (int e = 0; e < 2; ++e) {
    int c = tid + e * 256;
    int r = c >> 3, c8 = (c & 7) * 8;
    *(uint4*)&t[r][c8] =
        *(const uint4*)&V16[(size_t)(b * SEQ + s0 + r) * DMODEL + h * DK + c8];
  }
  __syncthreads();
  const int d = tid >> 2, sc0 = (tid & 3) * 16;
  #pragma unroll
  for (int e = 0; e < 16; ++e)
    Vt[((size_t)bh * DK + d) * SEQ + s0 + sc0 + e] = t[sc0 + e][d];
}

// ---------------------------------------------------------------------------
// ONE-PASS fused attention v3 (EXACT R13 config — best clean result, 189us,
// VGPR 52, no spill): 1024 thr / 16 waves, 16 q-rows, 128 cols/wave.
// No-max softmax; e as f16 pairs (cvt_pkrtz). Two q-set / bigger-stripe
// variants all spilled (R14/15/16) — do not revisit without a verified
// register-budget mechanism.
// MFMA maps (verified): A[lr][lg*8+j]; B[lg*8+j][lr]; D[lg*4+r][lr].
// ---------------------------------------------------------------------------
__global__ __launch_bounds__(1024) void attn_fused_kernel(
    const unsigned short* __restrict__ Qhi, const unsigned short* __restrict__ Qlo,
    const unsigned short* __restrict__ Khi, const unsigned int* __restrict__ bits,
    const unsigned short* __restrict__ Vt, float* __restrict__ attn,
    unsigned short* __restrict__ ctx16) {
  __shared__ unsigned short pbuf[16][16 * 76];  // 38912 B (also ctx reduce buf)
  __shared__ float smred[16][16];               // 1 KB (l partials)
  const int id = blockIdx.x;                    // 2048 blocks, XCD-swizzled
  const int xcd = id & 7, slot = id >> 3;       // slot 0..255
  const int bh = xcd + 8 * (slot & 1);
  const int qt = slot >> 1;                     // 0..127
  const int b = bh >> 3, h = bh & 7;
  const int tid = threadIdx.x, wv = tid >> 6, lane = tid & 63;
  const int lr = lane & 15, lg = lane >> 4;
  const int q0 = qt * 16;
  const int kw = wv * 128;  // wave's k-column base

  // Q frags (A layout: q-row = q0 + lr), hi+lo
  FragU qh[2], ql[2];
  #pragma unroll
  for (int dc = 0; dc < 2; ++dc) {
    const size_t qi = (size_t)(b * SEQ + q0 + lr) * DMODEL + h * DK + dc * 32 + lg * 8;
    qh[dc].u = *(const uint4*)&Qhi[qi];
    ql[dc].u = *(const uint4*)&Qlo[qi];
  }

  // ---- phase 1: e = exp(s/8) (masked -> 0) -> f16 pairs; l accumulates ----
  const float C = 0.125f * 1.44269504089f;  // fold scale into exp2
  PkU epk[8][2];
  float ls[4] = {0.f, 0.f, 0.f, 0.f};
  #pragma unroll
  for (int t = 0; t < 8; ++t) {
    FragU kh[2];
    #pragma unroll
    for (int dc = 0; dc < 2; ++dc) {
      const size_t kidx =
          (size_t)(b * SEQ + kw + t * 16 + lr) * DMODEL + h * DK + dc * 32 + lg * 8;
      kh[dc].u = *(const uint4*)&Khi[kidx];
    }
    f32x4 sa = {};
    #pragma unroll
    for (int dc = 0; dc < 2; ++dc) {
      sa = __builtin_amdgcn_mfma_f32_16x16x32_bf16(qh[dc].s, kh[dc].s, sa, 0, 0, 0);
      sa = __builtin_amdgcn_mfma_f32_16x16x32_bf16(ql[dc].s, kh[dc].s, sa, 0, 0, 0);
    }
    float ev[4];
    #pragma unroll
    for (int r = 0; r < 4; ++r) {
      const int q = q0 + lg * 4 + r;
      const unsigned int w = bits[((size_t)b * SEQ + q) * 64 + (kw >> 5) + (t >> 1)];
      const bool keep = (w >> (((t & 1) << 4) + lr)) & 1;
      const float e = keep ? exp2f(sa[r] * C) : 0.0f;
      ev[r] = e;
      ls[r] += e;
    }
    epk[t][0].h = __builtin_amdgcn_cvt_pkrtz(ev[0], ev[1]);
    epk[t][1].h = __builtin_amdgcn_cvt_pkrtz(ev[2], ev[3]);
  }

  // ---- l: shfl reduce over the 16-lane lr group, then cross-wave via LDS ----
  #pragma unroll
  for (int r = 0; r < 4; ++r) {
    #pragma unroll
    for (int off = 1; off < 16; off <<= 1) ls[r] += __shfl_xor(ls[r], off);
    if (lr == 0) smred[wv][lg * 4 + r] = ls[r];
  }
  __syncthreads();
  float il[4];
  #pragma unroll
  for (int r = 0; r < 4; ++r) {
    float l = 0.f;
    #pragma unroll
    for (int w2 = 0; w2 < 16; ++w2) l += smred[w2][lg * 4 + r];
    il[r] = 1.0f / l;
  }

  // ---- phase 2: p = e*il -> attn store + pbuf -> PV MFMA, per 64-col chunk --
  unsigned short* pb = pbuf[wv];
  f32x4 acc[4] = {};
  #pragma unroll
  for (int c = 0; c < 2; ++c) {
    #pragma unroll
    for (int tt = 0; tt < 4; ++tt) {
      const int t = c * 4 + tt;
      float pv4[4];
      pv4[0] = (float)epk[t][0].h.x * il[0];
      pv4[1] = (float)epk[t][0].h.y * il[1];
      pv4[2] = (float)epk[t][1].h.x * il[2];
      pv4[3] = (float)epk[t][1].h.y * il[3];
      #pragma unroll
      for (int r = 0; r < 4; ++r) {
        const int q = q0 + lg * 4 + r;
        attn[((size_t)bh * SEQ + q) * SEQ + kw + t * 16 + lr] = pv4[r];
        pb[(lg * 4 + r) * 76 + tt * 16 + lr] = f32_to_bf16(pv4[r]);
      }
    }
    #pragma unroll
    for (int dc2 = 0; dc2 < 2; ++dc2) {
      FragU pa;
      pa.u = *(const uint4*)&pb[lr * 76 + dc2 * 32 + lg * 8];
      #pragma unroll
      for (int dt = 0; dt < 4; ++dt) {
        FragU bv;
        bv.u = *(const uint4*)&Vt[((size_t)bh * DK + dt * 16 + lr) * SEQ + kw +
                                  c * 64 + dc2 * 32 + lg * 8];
        acc[dt] = __builtin_amdgcn_mfma_f32_16x16x32_bf16(pa.s, bv.s, acc[dt], 0, 0, 0);
      }
    }
  }

  // ---- 16-way ctx tree-reduce through pbuf (max 32 KB in flight) ----
  float* red = (float*)&pbuf[0][0];
  #pragma unroll 1
  for (int ofs = 8; ofs > 0; ofs >>= 1) {
    __syncthreads();
    if (wv >= ofs && wv < 2 * ofs) {
      float* dst = red + (size_t)(wv - ofs) * 1024;
      #pragma unroll
      for (int dt = 0; dt < 4; ++dt) *(f32x4*)&dst[dt * 256 + lane * 4] = acc[dt];
    }
    __syncthreads();
    if (wv < ofs) {
      const float* src = red + (size_t)wv * 1024;
      #pragma unroll
      for (int dt = 0; dt < 4; ++dt) acc[dt] += *(const f32x4*)&src[dt * 256 + lane * 4];
    }
  }
  if (wv == 0) {
    #pragma unroll
    for (int dt = 0; dt < 4; ++dt)
      #pragma unroll
      for (int r = 0; r < 4; ++r) {
        const int q = q0 + lg * 4 + r;
        ctx16[(size_t)(b * SEQ + q) * DMODEL + h * DK + dt * 16 + lr] =
            f32_to_bf16(acc[dt][r]);
      }
  }
}

// ---------------------------------------------------------------------------
extern "C" void kernel_launch(void* const* d_in, const int* in_sizes, int n_in,
                              void* d_out, int out_size, void* d_ws,
                              size_t ws_size, hipStream_t stream) {
  const float* q = (const float*)d_in[0];
  const float* k = (const float*)d_in[1];
  const float* v = (const float*)d_in[2];
  const int* mask = (const int*)d_in[3];
  const float* Wq = (const float*)d_in[4];
  const float* bq = (const float*)d_in[5];
  const float* Wk = (const float*)d_in[6];
  const float* bk = (const float*)d_in[7];
  const float* Wv = (const float*)d_in[8];
  const float* bv = (const float*)d_in[9];
  const float* Wo = (const float*)d_in[10];
  const float* bo = (const float*)d_in[11];

  float* out = (float*)d_out;
  float* attn = out + (size_t)BATCH * SEQ * DMODEL;

  char* w = (char*)d_ws;
  const size_t MB = 1u << 20;
  unsigned short* Qhi = (unsigned short*)(w + 0 * MB);     // flat [4096][512] bf16, 4MB
  unsigned short* Qlo = (unsigned short*)(w + 4 * MB);     // 4MB
  unsigned short* Khi = (unsigned short*)(w + 8 * MB);     // 4MB, single bf16
  unsigned short* WtHi4 = (unsigned short*)(w + 12 * MB);  // 4 x 512KB = 2MB
  unsigned short* WtLo4 = (unsigned short*)(w + 14 * MB);  // 2MB
  unsigned short* V16 = (unsigned short*)(w + 16 * MB);    // 4MB; dead after vtrans
  unsigned short* Vt = (unsigned short*)(w + 20 * MB);     // 4MB [bh][d][s]
  unsigned int* bits = (unsigned int*)(w + 24 * MB);       // 1 MB
  unsigned short* ctx16 = (unsigned short*)(w + 16 * MB);  // overlays V16

  const size_t WSTRIDE = (size_t)DMODEL * DMODEL;  // 262144 elements per pair

  dim3 blk(256);
  pack_mask_kernel<<<dim3(BATCH * SEQ), blk, 0, stream>>>(mask, bits);

  // all four weight splits in one launch (z: 0=Wq 1=Wk 2=Wv 3=Wo)
  wsplit4_kernel<<<dim3(8, 8, 4), blk, 0, stream>>>(Wq, Wk, Wv, Wo, WtHi4, WtLo4);

  proj_mfma_kernel<1><<<dim3(64, 8), blk, 0, stream>>>(
      q, nullptr, WtHi4 + 0 * WSTRIDE, WtLo4 + 0 * WSTRIDE, bq, nullptr, Qhi, Qlo);
  proj_mfma_kernel<2><<<dim3(64, 8), blk, 0, stream>>>(
      k, nullptr, WtHi4 + 1 * WSTRIDE, WtLo4 + 1 * WSTRIDE, bk, nullptr, Khi, nullptr);
  proj_mfma_kernel<2><<<dim3(64, 8), blk, 0, stream>>>(
      v, nullptr, WtHi4 + 2 * WSTRIDE, WtLo4 + 2 * WSTRIDE, bv, nullptr, V16, nullptr);
  vtrans_kernel<<<dim3(32, BH), blk, 0, stream>>>(V16, Vt);

  attn_fused_kernel<<<dim3(2048), dim3(1024), 0, stream>>>(Qhi, Qlo, Khi, bits,
                                                           Vt, attn, ctx16);

  proj_mfma_kernel<3><<<dim3(64, 8), blk, 0, stream>>>(
      nullptr, ctx16, WtHi4 + 3 * WSTRIDE, WtLo4 + 3 * WSTRIDE, bo, out, nullptr, nullptr);
}

// Round 18
// 251.060 us; speedup vs baseline: 1.3953x; 1.0473x over previous
//
#include <hip/hip_runtime.h>
#include <math.h>

#define HEADS 8
#define DK 64
#define DMODEL 512
#define BATCH 2
#define SEQ 2048
#define BH (BATCH * HEADS)

using f32x4 = __attribute__((ext_vector_type(4))) float;
using s16x8 = __attribute__((ext_vector_type(8))) short;
using fp16x2 = __attribute__((ext_vector_type(2))) __fp16;  // cvt_pkrtz's type

union FragU {
  uint4 u;
  s16x8 s;
  unsigned short us[8];
};
union PkU {
  fp16x2 h;
  unsigned int u;
};

__device__ __forceinline__ unsigned short f32_to_bf16(float f) {
  unsigned int u = __float_as_uint(f);
  u += 0x7fffu + ((u >> 16) & 1u);
  return (unsigned short)(u >> 16);
}
__device__ __forceinline__ float bf16_to_f32(unsigned short h) {
  return __uint_as_float(((unsigned int)h) << 16);
}

// ---------------------------------------------------------------------------
// mask int32 [B][S][S] -> packed bits [B][S][S/32]. One block per row.
// ---------------------------------------------------------------------------
__global__ __launch_bounds__(256) void pack_mask_kernel(
    const int* __restrict__ mask, unsigned int* __restrict__ bits) {
  const size_t row = blockIdx.x;  // B*S = 4096 rows
  const int wv = threadIdx.x >> 6, lane = threadIdx.x & 63;
  #pragma unroll
  for (int i = 0; i < 8; ++i) {
    const int c = wv * 512 + i * 64 + lane;
    unsigned long long bal = __ballot(mask[row * SEQ + c] != 0);
    if (lane == 0) {
      bits[row * 64 + (c >> 5)] = (unsigned int)bal;
      bits[row * 64 + (c >> 5) + 1] = (unsigned int)(bal >> 32);
    }
  }
}

// ---------------------------------------------------------------------------
// ALL FOUR W[512][512] f32 -> Wt hi/lo bf16 [n][k] in one launch.
// Grid (8,8,4); z selects the weight matrix; pair z lives at z*262144.
// ---------------------------------------------------------------------------
__global__ __launch_bounds__(256) void wsplit4_kernel(
    const float* __restrict__ W0, const float* __restrict__ W1,
    const float* __restrict__ W2, const float* __restrict__ W3,
    unsigned short* __restrict__ WtHi4, unsigned short* __restrict__ WtLo4) {
  __shared__ float t[64][65];
  const int z = blockIdx.z;
  const float* W = (z == 0) ? W0 : (z == 1) ? W1 : (z == 2) ? W2 : W3;
  unsigned short* WtHi = WtHi4 + (size_t)z * (DMODEL * DMODEL);
  unsigned short* WtLo = WtLo4 + (size_t)z * (DMODEL * DMODEL);
  const int k0 = blockIdx.x * 64, n0 = blockIdx.y * 64;
  const int tid = threadIdx.x;
  const int r = tid >> 2, c = (tid & 3) * 16;
  #pragma unroll
  for (int e = 0; e < 4; ++e) {
    f32x4 v = *(const f32x4*)&W[(size_t)(k0 + r) * DMODEL + n0 + c + e * 4];
    #pragma unroll
    for (int j = 0; j < 4; ++j) t[r][c + e * 4 + j] = v[j];
  }
  __syncthreads();
  const int rn = tid >> 2, ck = (tid & 3) * 16;
  #pragma unroll
  for (int half = 0; half < 2; ++half) {
    FragU hi, lo;
    #pragma unroll
    for (int e = 0; e < 8; ++e) {
      float x = t[ck + half * 8 + e][rn];
      unsigned short h = f32_to_bf16(x);
      hi.us[e] = h;
      lo.us[e] = f32_to_bf16(x - bf16_to_f32(h));
    }
    const size_t o = (size_t)(n0 + rn) * DMODEL + k0 + ck + half * 8;
    *(uint4*)&WtHi[o] = hi.u;
    *(uint4*)&WtLo[o] = lo.u;
  }
}

// ---------------------------------------------------------------------------
// MFMA projection GEMM (R8 structure): B-tile LDS-staged, coalesced
// transposed output. X layouts FLAT [4096][512].
// MODE 1: Y -> bf16 hi/lo pair (flat)
// MODE 2: Y -> bf16 (flat)
// MODE 3: X bf16 (ctx), Y -> f32 (flat)
// MODE 4: Y -> Vt[bh][d][s] bf16 directly (V path; vtrans fused into epilogue)
// ---------------------------------------------------------------------------
template <int MODE>
__global__ __launch_bounds__(256) void proj_mfma_kernel(
    const float* __restrict__ X, const unsigned short* __restrict__ X16,
    const unsigned short* __restrict__ WtHi,
    const unsigned short* __restrict__ WtLo, const float* __restrict__ bias,
    float* __restrict__ Yf, unsigned short* __restrict__ Yhi,
    unsigned short* __restrict__ Ylo) {
  __shared__ unsigned short BsHi[64][72];
  __shared__ unsigned short BsLo[64][72];
  const int tid = threadIdx.x, wv = tid >> 6, lane = tid & 63;
  const int lr = lane & 15, lg = lane >> 4;
  const int m0 = blockIdx.x * 64;
  const int mw = m0 + wv * 16;
  const int n0 = blockIdx.y * 64;

  f32x4 acc[4] = {};
  for (int k0 = 0; k0 < 512; k0 += 64) {
    FragU ah[2], al[2];
    #pragma unroll
    for (int dc = 0; dc < 2; ++dc) {
      const size_t xi = (size_t)(mw + lr) * DMODEL + k0 + dc * 32 + lg * 8;
      if (MODE == 3) {
        ah[dc].u = *(const uint4*)&X16[xi];
      } else {
        f32x4 x0 = *(const f32x4*)&X[xi];
        f32x4 x1 = *(const f32x4*)&X[xi + 4];
        #pragma unroll
        for (int t = 0; t < 4; ++t) {
          unsigned short h0 = f32_to_bf16(x0[t]);
          unsigned short h1 = f32_to_bf16(x1[t]);
          ah[dc].us[t] = h0;
          ah[dc].us[4 + t] = h1;
          al[dc].us[t] = f32_to_bf16(x0[t] - bf16_to_f32(h0));
          al[dc].us[4 + t] = f32_to_bf16(x1[t] - bf16_to_f32(h1));
        }
      }
    }
    __syncthreads();
    #pragma unroll
    for (int e = 0; e < 2; ++e) {
      const int rr = (tid >> 3) + e * 32;
      const int cc = (tid & 7) * 8;
      *(uint4*)&BsHi[rr][cc] =
          *(const uint4*)&WtHi[(size_t)(n0 + rr) * DMODEL + k0 + cc];
      *(uint4*)&BsLo[rr][cc] =
          *(const uint4*)&WtLo[(size_t)(n0 + rr) * DMODEL + k0 + cc];
    }
    __syncthreads();
    #pragma unroll
    for (int jt = 0; jt < 4; ++jt) {
      #pragma unroll
      for (int dc = 0; dc < 2; ++dc) {
        FragU bh, bl;
        bh.u = *(const uint4*)&BsHi[jt * 16 + lr][dc * 32 + lg * 8];
        bl.u = *(const uint4*)&BsLo[jt * 16 + lr][dc * 32 + lg * 8];
        acc[jt] = __builtin_amdgcn_mfma_f32_16x16x32_bf16(ah[dc].s, bh.s, acc[jt], 0, 0, 0);
        acc[jt] = __builtin_amdgcn_mfma_f32_16x16x32_bf16(ah[dc].s, bl.s, acc[jt], 0, 0, 0);
        if (MODE != 3)
          acc[jt] = __builtin_amdgcn_mfma_f32_16x16x32_bf16(al[dc].s, bh.s, acc[jt], 0, 0, 0);
      }
    }
  }

  if (MODE == 3) {
    #pragma unroll
    for (int jt = 0; jt < 4; ++jt) {
      const int n = n0 + jt * 16 + lr;
      const float bi = bias[n];
      #pragma unroll
      for (int r = 0; r < 4; ++r)
        Yf[(size_t)(mw + lg * 4 + r) * DMODEL + n] = acc[jt][r] + bi;
    }
  } else {
    __syncthreads();
    #pragma unroll
    for (int jt = 0; jt < 4; ++jt) {
      const int n = jt * 16 + lr;
      const float bi = bias[n0 + n];
      #pragma unroll
      for (int r = 0; r < 4; ++r) {
        const float v = acc[jt][r] + bi;
        const int row = wv * 16 + lg * 4 + r;
        unsigned short hi = f32_to_bf16(v);
        BsHi[row][n] = hi;
        if (MODE == 1) BsLo[row][n] = f32_to_bf16(v - bf16_to_f32(hi));
      }
    }
    __syncthreads();
    if (MODE == 4) {
      // transposed write: Vt[(b*8+h)*64 + d][s0 .. s0+63] (vtrans pattern)
      const int b2 = m0 >> 11, s0 = m0 & 2047, hh = n0 >> 6;
      const int d = tid >> 2, sc = (tid & 3) * 16;
      #pragma unroll
      for (int e = 0; e < 16; ++e)
        Yhi[((size_t)(b2 * HEADS + hh) * DK + d) * SEQ + s0 + sc + e] =
            BsHi[sc + e][d];
    } else {
      #pragma unroll
      for (int p = 0; p < 2; ++p) {
        const int row = (tid >> 3) + p * 32;
        const int ch = (tid & 7) * 8;
        const size_t o = (size_t)(m0 + row) * DMODEL + n0 + ch;
        *(uint4*)&Yhi[o] = *(uint4*)&BsHi[row][ch];
        if (MODE == 1) *(uint4*)&Ylo[o] = *(uint4*)&BsLo[row][ch];
      }
    }
  }
}

// ---------------------------------------------------------------------------
// ONE-PASS fused attention v3 (R13 config, best clean: 189us, VGPR 52) with
// NON-TEMPORAL p-stores: the 266 MB attn stream is write-once/never-read —
// nt stores keep it from evicting the L2-resident K panels. ctx16 stays
// normal (re-read by out-proj).
// 1024 thr / 16 waves, 16 q-rows, 128 cols/wave; no-max softmax; e as f16.
// MFMA maps (verified): A[lr][lg*8+j]; B[lg*8+j][lr]; D[lg*4+r][lr].
// ---------------------------------------------------------------------------
__global__ __launch_bounds__(1024) void attn_fused_kernel(
    const unsigned short* __restrict__ Qhi, const unsigned short* __restrict__ Qlo,
    const unsigned short* __restrict__ Khi, const unsigned int* __restrict__ bits,
    const unsigned short* __restrict__ Vt, float* __restrict__ attn,
    unsigned short* __restrict__ ctx16) {
  __shared__ unsigned short pbuf[16][16 * 76];  // 38912 B (also ctx reduce buf)
  __shared__ float smred[16][16];               // 1 KB (l partials)
  const int id = blockIdx.x;                    // 2048 blocks, XCD-swizzled
  const int xcd = id & 7, slot = id >> 3;       // slot 0..255
  const int bh = xcd + 8 * (slot & 1);
  const int qt = slot >> 1;                     // 0..127
  const int b = bh >> 3, h = bh & 7;
  const int tid = threadIdx.x, wv = tid >> 6, lane = tid & 63;
  const int lr = lane & 15, lg = lane >> 4;
  const int q0 = qt * 16;
  const int kw = wv * 128;  // wave's k-column base

  // Q frags (A layout: q-row = q0 + lr), hi+lo
  FragU qh[2], ql[2];
  #pragma unroll
  for (int dc = 0; dc < 2; ++dc) {
    const size_t qi = (size_t)(b * SEQ + q0 + lr) * DMODEL + h * DK + dc * 32 + lg * 8;
    qh[dc].u = *(const uint4*)&Qhi[qi];
    ql[dc].u = *(const uint4*)&Qlo[qi];
  }

  // ---- phase 1: e = exp(s/8) (masked -> 0) -> f16 pairs; l accumulates ----
  const float C = 0.125f * 1.44269504089f;  // fold scale into exp2
  PkU epk[8][2];
  float ls[4] = {0.f, 0.f, 0.f, 0.f};
  #pragma unroll
  for (int t = 0; t < 8; ++t) {
    FragU kh[2];
    #pragma unroll
    for (int dc = 0; dc < 2; ++dc) {
      const size_t kidx =
          (size_t)(b * SEQ + kw + t * 16 + lr) * DMODEL + h * DK + dc * 32 + lg * 8;
      kh[dc].u = *(const uint4*)&Khi[kidx];
    }
    f32x4 sa = {};
    #pragma unroll
    for (int dc = 0; dc < 2; ++dc) {
      sa = __builtin_amdgcn_mfma_f32_16x16x32_bf16(qh[dc].s, kh[dc].s, sa, 0, 0, 0);
      sa = __builtin_amdgcn_mfma_f32_16x16x32_bf16(ql[dc].s, kh[dc].s, sa, 0, 0, 0);
    }
    float ev[4];
    #pragma unroll
    for (int r = 0; r < 4; ++r) {
      const int q = q0 + lg * 4 + r;
      const unsigned int w = bits[((size_t)b * SEQ + q) * 64 + (kw >> 5) + (t >> 1)];
      const bool keep = (w >> (((t & 1) << 4) + lr)) & 1;
      const float e = keep ? exp2f(sa[r] * C) : 0.0f;
      ev[r] = e;
      ls[r] += e;
    }
    epk[t][0].h = __builtin_amdgcn_cvt_pkrtz(ev[0], ev[1]);
    epk[t][1].h = __builtin_amdgcn_cvt_pkrtz(ev[2], ev[3]);
  }

  // ---- l: shfl reduce over the 16-lane lr group, then cross-wave via LDS ----
  #pragma unroll
  for (int r = 0; r < 4; ++r) {
    #pragma unroll
    for (int off = 1; off < 16; off <<= 1) ls[r] += __shfl_xor(ls[r], off);
    if (lr == 0) smred[wv][lg * 4 + r] = ls[r];
  }
  __syncthreads();
  float il[4];
  #pragma unroll
  for (int r = 0; r < 4; ++r) {
    float l = 0.f;
    #pragma unroll
    for (int w2 = 0; w2 < 16; ++w2) l += smred[w2][lg * 4 + r];
    il[r] = 1.0f / l;
  }

  // ---- phase 2: p = e*il -> nt attn store + pbuf -> PV MFMA ----
  unsigned short* pb = pbuf[wv];
  f32x4 acc[4] = {};
  #pragma unroll
  for (int c = 0; c < 2; ++c) {
    #pragma unroll
    for (int tt = 0; tt < 4; ++tt) {
      const int t = c * 4 + tt;
      float pv4[4];
      pv4[0] = (float)epk[t][0].h.x * il[0];
      pv4[1] = (float)epk[t][0].h.y * il[1];
      pv4[2] = (float)epk[t][1].h.x * il[2];
      pv4[3] = (float)epk[t][1].h.y * il[3];
      #pragma unroll
      for (int r = 0; r < 4; ++r) {
        const int q = q0 + lg * 4 + r;
        __builtin_nontemporal_store(
            pv4[r], &attn[((size_t)bh * SEQ + q) * SEQ + kw + t * 16 + lr]);
        pb[(lg * 4 + r) * 76 + tt * 16 + lr] = f32_to_bf16(pv4[r]);
      }
    }
    #pragma unroll
    for (int dc2 = 0; dc2 < 2; ++dc2) {
      FragU pa;
      pa.u = *(const uint4*)&pb[lr * 76 + dc2 * 32 + lg * 8];
      #pragma unroll
      for (int dt = 0; dt < 4; ++dt) {
        FragU bv;
        bv.u = *(const uint4*)&Vt[((size_t)bh * DK + dt * 16 + lr) * SEQ + kw +
                                  c * 64 + dc2 * 32 + lg * 8];
        acc[dt] = __builtin_amdgcn_mfma_f32_16x16x32_bf16(pa.s, bv.s, acc[dt], 0, 0, 0);
      }
    }
  }

  // ---- 16-way ctx tree-reduce through pbuf (max 32 KB in flight) ----
  float* red = (float*)&pbuf[0][0];
  #pragma unroll 1
  for (int ofs = 8; ofs > 0; ofs >>= 1) {
    __syncthreads();
    if (wv >= ofs && wv < 2 * ofs) {
      float* dst = red + (size_t)(wv - ofs) * 1024;
      #pragma unroll
      for (int dt = 0; dt < 4; ++dt) *(f32x4*)&dst[dt * 256 + lane * 4] = acc[dt];
    }
    __syncthreads();
    if (wv < ofs) {
      const float* src = red + (size_t)wv * 1024;
      #pragma unroll
      for (int dt = 0; dt < 4; ++dt) acc[dt] += *(const f32x4*)&src[dt * 256 + lane * 4];
    }
  }
  if (wv == 0) {
    #pragma unroll
    for (int dt = 0; dt < 4; ++dt)
      #pragma unroll
      for (int r = 0; r < 4; ++r) {
        const int q = q0 + lg * 4 + r;
        ctx16[(size_t)(b * SEQ + q) * DMODEL + h * DK + dt * 16 + lr] =
            f32_to_bf16(acc[dt][r]);
      }
  }
}

// ---------------------------------------------------------------------------
extern "C" void kernel_launch(void* const* d_in, const int* in_sizes, int n_in,
                              void* d_out, int out_size, void* d_ws,
                              size_t ws_size, hipStream_t stream) {
  const float* q = (const float*)d_in[0];
  const float* k = (const float*)d_in[1];
  const float* v = (const float*)d_in[2];
  const int* mask = (const int*)d_in[3];
  const float* Wq = (const float*)d_in[4];
  const float* bq = (const float*)d_in[5];
  const float* Wk = (const float*)d_in[6];
  const float* bk = (const float*)d_in[7];
  const float* Wv = (const float*)d_in[8];
  const float* bv = (const float*)d_in[9];
  const float* Wo = (const float*)d_in[10];
  const float* bo = (const float*)d_in[11];

  float* out = (float*)d_out;
  float* attn = out + (size_t)BATCH * SEQ * DMODEL;

  char* w = (char*)d_ws;
  const size_t MB = 1u << 20;
  unsigned short* Qhi = (unsigned short*)(w + 0 * MB);     // flat [4096][512] bf16, 4MB
  unsigned short* Qlo = (unsigned short*)(w + 4 * MB);     // 4MB
  unsigned short* Khi = (unsigned short*)(w + 8 * MB);     // 4MB, single bf16
  unsigned short* WtHi4 = (unsigned short*)(w + 12 * MB);  // 4 x 512KB = 2MB
  unsigned short* WtLo4 = (unsigned short*)(w + 14 * MB);  // 2MB
  unsigned short* ctx16 = (unsigned short*)(w + 16 * MB);  // 4MB
  unsigned short* Vt = (unsigned short*)(w + 20 * MB);     // 4MB [bh][d][s]
  unsigned int* bits = (unsigned int*)(w + 24 * MB);       // 1 MB

  const size_t WSTRIDE = (size_t)DMODEL * DMODEL;  // 262144 elements per pair

  dim3 blk(256);
  pack_mask_kernel<<<dim3(BATCH * SEQ), blk, 0, stream>>>(mask, bits);

  // all four weight splits in one launch (z: 0=Wq 1=Wk 2=Wv 3=Wo)
  wsplit4_kernel<<<dim3(8, 8, 4), blk, 0, stream>>>(Wq, Wk, Wv, Wo, WtHi4, WtLo4);

  proj_mfma_kernel<1><<<dim3(64, 8), blk, 0, stream>>>(
      q, nullptr, WtHi4 + 0 * WSTRIDE, WtLo4 + 0 * WSTRIDE, bq, nullptr, Qhi, Qlo);
  proj_mfma_kernel<2><<<dim3(64, 8), blk, 0, stream>>>(
      k, nullptr, WtHi4 + 1 * WSTRIDE, WtLo4 + 1 * WSTRIDE, bk, nullptr, Khi, nullptr);
  // V projection writes Vt[bh][d][s] directly (vtrans fused)
  proj_mfma_kernel<4><<<dim3(64, 8), blk, 0, stream>>>(
      v, nullptr, WtHi4 + 2 * WSTRIDE, WtLo4 + 2 * WSTRIDE, bv, nullptr, Vt, nullptr);

  attn_fused_kernel<<<dim3(2048), dim3(1024), 0, stream>>>(Qhi, Qlo, Khi, bits,
                                                           Vt, attn, ctx16);

  proj_mfma_kernel<3><<<dim3(64, 8), blk, 0, stream>>>(
      nullptr, ctx16, WtHi4 + 3 * WSTRIDE, WtLo4 + 3 * WSTRIDE, bo, out, nullptr, nullptr);
}

// Round 19
// 251.008 us; speedup vs baseline: 1.3956x; 1.0002x over previous
//
#include <hip/hip_runtime.h>
#include <math.h>

#define HEADS 8
#define DK 64
#define DMODEL 512
#define BATCH 2
#define SEQ 2048
#define BH (BATCH * HEADS)

using f32x4 = __attribute__((ext_vector_type(4))) float;
using s16x8 = __attribute__((ext_vector_type(8))) short;
using fp16x2 = __attribute__((ext_vector_type(2))) __fp16;  // cvt_pkrtz's type

union FragU {
  uint4 u;
  s16x8 s;
  unsigned short us[8];
};
union PkU {
  fp16x2 h;
  unsigned int u;
};

__device__ __forceinline__ unsigned short f32_to_bf16(float f) {
  unsigned int u = __float_as_uint(f);
  u += 0x7fffu + ((u >> 16) & 1u);
  return (unsigned short)(u >> 16);
}
__device__ __forceinline__ float bf16_to_f32(unsigned short h) {
  return __uint_as_float(((unsigned int)h) << 16);
}

// ---------------------------------------------------------------------------
// mask int32 [B][S][S] -> packed bits [B][S][S/32]. One block per row.
// ---------------------------------------------------------------------------
__global__ __launch_bounds__(256) void pack_mask_kernel(
    const int* __restrict__ mask, unsigned int* __restrict__ bits) {
  const size_t row = blockIdx.x;  // B*S = 4096 rows
  const int wv = threadIdx.x >> 6, lane = threadIdx.x & 63;
  #pragma unroll
  for (int i = 0; i < 8; ++i) {
    const int c = wv * 512 + i * 64 + lane;
    unsigned long long bal = __ballot(mask[row * SEQ + c] != 0);
    if (lane == 0) {
      bits[row * 64 + (c >> 5)] = (unsigned int)bal;
      bits[row * 64 + (c >> 5) + 1] = (unsigned int)(bal >> 32);
    }
  }
}

// ---------------------------------------------------------------------------
// ALL FOUR W[512][512] f32 -> Wt hi/lo bf16 [n][k] in one launch.
// Grid (8,8,4); z selects the weight matrix; pair z lives at z*262144.
// ---------------------------------------------------------------------------
__global__ __launch_bounds__(256) void wsplit4_kernel(
    const float* __restrict__ W0, const float* __restrict__ W1,
    const float* __restrict__ W2, const float* __restrict__ W3,
    unsigned short* __restrict__ WtHi4, unsigned short* __restrict__ WtLo4) {
  __shared__ float t[64][65];
  const int z = blockIdx.z;
  const float* W = (z == 0) ? W0 : (z == 1) ? W1 : (z == 2) ? W2 : W3;
  unsigned short* WtHi = WtHi4 + (size_t)z * (DMODEL * DMODEL);
  unsigned short* WtLo = WtLo4 + (size_t)z * (DMODEL * DMODEL);
  const int k0 = blockIdx.x * 64, n0 = blockIdx.y * 64;
  const int tid = threadIdx.x;
  const int r = tid >> 2, c = (tid & 3) * 16;
  #pragma unroll
  for (int e = 0; e < 4; ++e) {
    f32x4 v = *(const f32x4*)&W[(size_t)(k0 + r) * DMODEL + n0 + c + e * 4];
    #pragma unroll
    for (int j = 0; j < 4; ++j) t[r][c + e * 4 + j] = v[j];
  }
  __syncthreads();
  const int rn = tid >> 2, ck = (tid & 3) * 16;
  #pragma unroll
  for (int half = 0; half < 2; ++half) {
    FragU hi, lo;
    #pragma unroll
    for (int e = 0; e < 8; ++e) {
      float x = t[ck + half * 8 + e][rn];
      unsigned short h = f32_to_bf16(x);
      hi.us[e] = h;
      lo.us[e] = f32_to_bf16(x - bf16_to_f32(h));
    }
    const size_t o = (size_t)(n0 + rn) * DMODEL + k0 + ck + half * 8;
    *(uint4*)&WtHi[o] = hi.u;
    *(uint4*)&WtLo[o] = lo.u;
  }
}

// ---------------------------------------------------------------------------
// Fused Q/K/V projection: one launch, grid (64,8,3). z=0: Q -> bf16 hi/lo
// flat; z=1: K -> bf16 flat; z=2: V -> Vt[bh][d][s] (transposed epilogue).
// Main MFMA loop identical across z (3 MFMAs: ah*bh, ah*bl, al*bh).
// ---------------------------------------------------------------------------
__global__ __launch_bounds__(256) void proj_qkv_kernel(
    const float* __restrict__ Xq, const float* __restrict__ Xk,
    const float* __restrict__ Xv, const unsigned short* __restrict__ WtHi4,
    const unsigned short* __restrict__ WtLo4, const float* __restrict__ bq,
    const float* __restrict__ bk, const float* __restrict__ bv,
    unsigned short* __restrict__ Qhi, unsigned short* __restrict__ Qlo,
    unsigned short* __restrict__ Khi, unsigned short* __restrict__ Vt) {
  __shared__ unsigned short BsHi[64][72];
  __shared__ unsigned short BsLo[64][72];
  const int z = blockIdx.z;
  const float* X = (z == 0) ? Xq : (z == 1) ? Xk : Xv;
  const float* bias = (z == 0) ? bq : (z == 1) ? bk : bv;
  const unsigned short* WtHi = WtHi4 + (size_t)z * (DMODEL * DMODEL);
  const unsigned short* WtLo = WtLo4 + (size_t)z * (DMODEL * DMODEL);

  const int tid = threadIdx.x, wv = tid >> 6, lane = tid & 63;
  const int lr = lane & 15, lg = lane >> 4;
  const int m0 = blockIdx.x * 64;
  const int mw = m0 + wv * 16;
  const int n0 = blockIdx.y * 64;

  f32x4 acc[4] = {};
  for (int k0 = 0; k0 < 512; k0 += 64) {
    FragU ah[2], al[2];
    #pragma unroll
    for (int dc = 0; dc < 2; ++dc) {
      const size_t xi = (size_t)(mw + lr) * DMODEL + k0 + dc * 32 + lg * 8;
      f32x4 x0 = *(const f32x4*)&X[xi];
      f32x4 x1 = *(const f32x4*)&X[xi + 4];
      #pragma unroll
      for (int t = 0; t < 4; ++t) {
        unsigned short h0 = f32_to_bf16(x0[t]);
        unsigned short h1 = f32_to_bf16(x1[t]);
        ah[dc].us[t] = h0;
        ah[dc].us[4 + t] = h1;
        al[dc].us[t] = f32_to_bf16(x0[t] - bf16_to_f32(h0));
        al[dc].us[4 + t] = f32_to_bf16(x1[t] - bf16_to_f32(h1));
      }
    }
    __syncthreads();
    #pragma unroll
    for (int e = 0; e < 2; ++e) {
      const int rr = (tid >> 3) + e * 32;
      const int cc = (tid & 7) * 8;
      *(uint4*)&BsHi[rr][cc] =
          *(const uint4*)&WtHi[(size_t)(n0 + rr) * DMODEL + k0 + cc];
      *(uint4*)&BsLo[rr][cc] =
          *(const uint4*)&WtLo[(size_t)(n0 + rr) * DMODEL + k0 + cc];
    }
    __syncthreads();
    #pragma unroll
    for (int jt = 0; jt < 4; ++jt) {
      #pragma unroll
      for (int dc = 0; dc < 2; ++dc) {
        FragU bh, bl;
        bh.u = *(const uint4*)&BsHi[jt * 16 + lr][dc * 32 + lg * 8];
        bl.u = *(const uint4*)&BsLo[jt * 16 + lr][dc * 32 + lg * 8];
        acc[jt] = __builtin_amdgcn_mfma_f32_16x16x32_bf16(ah[dc].s, bh.s, acc[jt], 0, 0, 0);
        acc[jt] = __builtin_amdgcn_mfma_f32_16x16x32_bf16(ah[dc].s, bl.s, acc[jt], 0, 0, 0);
        acc[jt] = __builtin_amdgcn_mfma_f32_16x16x32_bf16(al[dc].s, bh.s, acc[jt], 0, 0, 0);
      }
    }
  }

  __syncthreads();  // reuse Bs as output staging
  #pragma unroll
  for (int jt = 0; jt < 4; ++jt) {
    const int n = jt * 16 + lr;
    const float bi = bias[n0 + n];
    #pragma unroll
    for (int r = 0; r < 4; ++r) {
      const float v = acc[jt][r] + bi;
      const int row = wv * 16 + lg * 4 + r;
      unsigned short hi = f32_to_bf16(v);
      BsHi[row][n] = hi;
      if (z == 0) BsLo[row][n] = f32_to_bf16(v - bf16_to_f32(hi));
    }
  }
  __syncthreads();
  if (z == 2) {
    // transposed write: Vt[(b*8+h)*64 + d][s0 .. s0+63] (vtrans pattern)
    const int b2 = m0 >> 11, s0 = m0 & 2047, hh = n0 >> 6;
    const int d = tid >> 2, sc = (tid & 3) * 16;
    #pragma unroll
    for (int e = 0; e < 16; ++e)
      Vt[((size_t)(b2 * HEADS + hh) * DK + d) * SEQ + s0 + sc + e] =
          BsHi[sc + e][d];
  } else {
    unsigned short* Yhi = (z == 0) ? Qhi : Khi;
    #pragma unroll
    for (int p = 0; p < 2; ++p) {
      const int row = (tid >> 3) + p * 32;
      const int ch = (tid & 7) * 8;
      const size_t o = (size_t)(m0 + row) * DMODEL + n0 + ch;
      *(uint4*)&Yhi[o] = *(uint4*)&BsHi[row][ch];
      if (z == 0) *(uint4*)&Qlo[o] = *(uint4*)&BsLo[row][ch];
    }
  }
}

// ---------------------------------------------------------------------------
// Output projection (MODE 3 of old proj): X = ctx bf16, Y = out f32.
// ---------------------------------------------------------------------------
__global__ __launch_bounds__(256) void proj_out_kernel(
    const unsigned short* __restrict__ X16, const unsigned short* __restrict__ WtHi,
    const unsigned short* __restrict__ WtLo, const float* __restrict__ bias,
    float* __restrict__ Yf) {
  __shared__ unsigned short BsHi[64][72];
  __shared__ unsigned short BsLo[64][72];
  const int tid = threadIdx.x, wv = tid >> 6, lane = tid & 63;
  const int lr = lane & 15, lg = lane >> 4;
  const int m0 = blockIdx.x * 64;
  const int mw = m0 + wv * 16;
  const int n0 = blockIdx.y * 64;

  f32x4 acc[4] = {};
  for (int k0 = 0; k0 < 512; k0 += 64) {
    FragU ah[2];
    #pragma unroll
    for (int dc = 0; dc < 2; ++dc) {
      const size_t xi = (size_t)(mw + lr) * DMODEL + k0 + dc * 32 + lg * 8;
      ah[dc].u = *(const uint4*)&X16[xi];
    }
    __syncthreads();
    #pragma unroll
    for (int e = 0; e < 2; ++e) {
      const int rr = (tid >> 3) + e * 32;
      const int cc = (tid & 7) * 8;
      *(uint4*)&BsHi[rr][cc] =
          *(const uint4*)&WtHi[(size_t)(n0 + rr) * DMODEL + k0 + cc];
      *(uint4*)&BsLo[rr][cc] =
          *(const uint4*)&WtLo[(size_t)(n0 + rr) * DMODEL + k0 + cc];
    }
    __syncthreads();
    #pragma unroll
    for (int jt = 0; jt < 4; ++jt) {
      #pragma unroll
      for (int dc = 0; dc < 2; ++dc) {
        FragU bh, bl;
        bh.u = *(const uint4*)&BsHi[jt * 16 + lr][dc * 32 + lg * 8];
        bl.u = *(const uint4*)&BsLo[jt * 16 + lr][dc * 32 + lg * 8];
        acc[jt] = __builtin_amdgcn_mfma_f32_16x16x32_bf16(ah[dc].s, bh.s, acc[jt], 0, 0, 0);
        acc[jt] = __builtin_amdgcn_mfma_f32_16x16x32_bf16(ah[dc].s, bl.s, acc[jt], 0, 0, 0);
      }
    }
  }
  #pragma unroll
  for (int jt = 0; jt < 4; ++jt) {
    const int n = n0 + jt * 16 + lr;
    const float bi = bias[n];
    #pragma unroll
    for (int r = 0; r < 4; ++r)
      Yf[(size_t)(mw + lg * 4 + r) * DMODEL + n] = acc[jt][r] + bi;
  }
}

// ---------------------------------------------------------------------------
// ONE-PASS fused attention (R13 config + uint4 bits preload; plain p-stores —
// nt-store variant REGRESSED in R18: +74MB partial-line write traffic).
// 1024 thr / 16 waves, 16 q-rows, 128 cols/wave; no-max softmax; e as f16.
// MFMA maps (verified): A[lr][lg*8+j]; B[lg*8+j][lr]; D[lg*4+r][lr].
// ---------------------------------------------------------------------------
__global__ __launch_bounds__(1024) void attn_fused_kernel(
    const unsigned short* __restrict__ Qhi, const unsigned short* __restrict__ Qlo,
    const unsigned short* __restrict__ Khi, const unsigned int* __restrict__ bits,
    const unsigned short* __restrict__ Vt, float* __restrict__ attn,
    unsigned short* __restrict__ ctx16) {
  __shared__ unsigned short pbuf[16][16 * 76];  // 38912 B (also ctx reduce buf)
  __shared__ float smred[16][16];               // 1 KB (l partials)
  const int id = blockIdx.x;                    // 2048 blocks, XCD-swizzled
  const int xcd = id & 7, slot = id >> 3;       // slot 0..255
  const int bh = xcd + 8 * (slot & 1);
  const int qt = slot >> 1;                     // 0..127
  const int b = bh >> 3, h = bh & 7;
  const int tid = threadIdx.x, wv = tid >> 6, lane = tid & 63;
  const int lr = lane & 15, lg = lane >> 4;
  const int q0 = qt * 16;
  const int kw = wv * 128;  // wave's k-column base

  // Q frags (A layout: q-row = q0 + lr), hi+lo
  FragU qh[2], ql[2];
  #pragma unroll
  for (int dc = 0; dc < 2; ++dc) {
    const size_t qi = (size_t)(b * SEQ + q0 + lr) * DMODEL + h * DK + dc * 32 + lg * 8;
    qh[dc].u = *(const uint4*)&Qhi[qi];
    ql[dc].u = *(const uint4*)&Qlo[qi];
  }
  // mask words for this wave's 128 cols x 4 rows: one uint4 per row
  uint4 mw4[4];
  #pragma unroll
  for (int r = 0; r < 4; ++r) {
    const int q = q0 + lg * 4 + r;
    mw4[r] = *(const uint4*)&bits[((size_t)b * SEQ + q) * 64 + (kw >> 5)];
  }

  // ---- phase 1: e = exp(s/8) (masked -> 0) -> f16 pairs; l accumulates ----
  const float C = 0.125f * 1.44269504089f;  // fold scale into exp2
  PkU epk[8][2];
  float ls[4] = {0.f, 0.f, 0.f, 0.f};
  #pragma unroll
  for (int t = 0; t < 8; ++t) {
    FragU kh[2];
    #pragma unroll
    for (int dc = 0; dc < 2; ++dc) {
      const size_t kidx =
          (size_t)(b * SEQ + kw + t * 16 + lr) * DMODEL + h * DK + dc * 32 + lg * 8;
      kh[dc].u = *(const uint4*)&Khi[kidx];
    }
    f32x4 sa = {};
    #pragma unroll
    for (int dc = 0; dc < 2; ++dc) {
      sa = __builtin_amdgcn_mfma_f32_16x16x32_bf16(qh[dc].s, kh[dc].s, sa, 0, 0, 0);
      sa = __builtin_amdgcn_mfma_f32_16x16x32_bf16(ql[dc].s, kh[dc].s, sa, 0, 0, 0);
    }
    float ev[4];
    #pragma unroll
    for (int r = 0; r < 4; ++r) {
      const unsigned int w =
          (t >> 1) == 0 ? mw4[r].x : (t >> 1) == 1 ? mw4[r].y
          : (t >> 1) == 2 ? mw4[r].z : mw4[r].w;
      const bool keep = (w >> (((t & 1) << 4) + lr)) & 1;
      const float e = keep ? exp2f(sa[r] * C) : 0.0f;
      ev[r] = e;
      ls[r] += e;
    }
    epk[t][0].h = __builtin_amdgcn_cvt_pkrtz(ev[0], ev[1]);
    epk[t][1].h = __builtin_amdgcn_cvt_pkrtz(ev[2], ev[3]);
  }

  // ---- l: shfl reduce over the 16-lane lr group, then cross-wave via LDS ----
  #pragma unroll
  for (int r = 0; r < 4; ++r) {
    #pragma unroll
    for (int off = 1; off < 16; off <<= 1) ls[r] += __shfl_xor(ls[r], off);
    if (lr == 0) smred[wv][lg * 4 + r] = ls[r];
  }
  __syncthreads();
  float il[4];
  #pragma unroll
  for (int r = 0; r < 4; ++r) {
    float l = 0.f;
    #pragma unroll
    for (int w2 = 0; w2 < 16; ++w2) l += smred[w2][lg * 4 + r];
    il[r] = 1.0f / l;
  }

  // ---- phase 2: p = e*il -> attn store + pbuf -> PV MFMA, per 64-col chunk --
  unsigned short* pb = pbuf[wv];
  f32x4 acc[4] = {};
  #pragma unroll
  for (int c = 0; c < 2; ++c) {
    #pragma unroll
    for (int tt = 0; tt < 4; ++tt) {
      const int t = c * 4 + tt;
      float pv4[4];
      pv4[0] = (float)epk[t][0].h.x * il[0];
      pv4[1] = (float)epk[t][0].h.y * il[1];
      pv4[2] = (float)epk[t][1].h.x * il[2];
      pv4[3] = (float)epk[t][1].h.y * il[3];
      #pragma unroll
      for (int r = 0; r < 4; ++r) {
        const int q = q0 + lg * 4 + r;
        attn[((size_t)bh * SEQ + q) * SEQ + kw + t * 16 + lr] = pv4[r];
        pb[(lg * 4 + r) * 76 + tt * 16 + lr] = f32_to_bf16(pv4[r]);
      }
    }
    #pragma unroll
    for (int dc2 = 0; dc2 < 2; ++dc2) {
      FragU pa;
      pa.u = *(const uint4*)&pb[lr * 76 + dc2 * 32 + lg * 8];
      #pragma unroll
      for (int dt = 0; dt < 4; ++dt) {
        FragU bv;
        bv.u = *(const uint4*)&Vt[((size_t)bh * DK + dt * 16 + lr) * SEQ + kw +
                                  c * 64 + dc2 * 32 + lg * 8];
        acc[dt] = __builtin_amdgcn_mfma_f32_16x16x32_bf16(pa.s, bv.s, acc[dt], 0, 0, 0);
      }
    }
  }

  // ---- 16-way ctx tree-reduce through pbuf (max 32 KB in flight) ----
  float* red = (float*)&pbuf[0][0];
  #pragma unroll 1
  for (int ofs = 8; ofs > 0; ofs >>= 1) {
    __syncthreads();
    if (wv >= ofs && wv < 2 * ofs) {
      float* dst = red + (size_t)(wv - ofs) * 1024;
      #pragma unroll
      for (int dt = 0; dt < 4; ++dt) *(f32x4*)&dst[dt * 256 + lane * 4] = acc[dt];
    }
    __syncthreads();
    if (wv < ofs) {
      const float* src = red + (size_t)wv * 1024;
      #pragma unroll
      for (int dt = 0; dt < 4; ++dt) acc[dt] += *(const f32x4*)&src[dt * 256 + lane * 4];
    }
  }
  if (wv == 0) {
    #pragma unroll
    for (int dt = 0; dt < 4; ++dt)
      #pragma unroll
      for (int r = 0; r < 4; ++r) {
        const int q = q0 + lg * 4 + r;
        ctx16[(size_t)(b * SEQ + q) * DMODEL + h * DK + dt * 16 + lr] =
            f32_to_bf16(acc[dt][r]);
      }
  }
}

// ---------------------------------------------------------------------------
extern "C" void kernel_launch(void* const* d_in, const int* in_sizes, int n_in,
                              void* d_out, int out_size, void* d_ws,
                              size_t ws_size, hipStream_t stream) {
  const float* q = (const float*)d_in[0];
  const float* k = (const float*)d_in[1];
  const float* v = (const float*)d_in[2];
  const int* mask = (const int*)d_in[3];
  const float* Wq = (const float*)d_in[4];
  const float* bq = (const float*)d_in[5];
  const float* Wk = (const float*)d_in[6];
  const float* bk = (const float*)d_in[7];
  const float* Wv = (const float*)d_in[8];
  const float* bv = (const float*)d_in[9];
  const float* Wo = (const float*)d_in[10];
  const float* bo = (const float*)d_in[11];

  float* out = (float*)d_out;
  float* attn = out + (size_t)BATCH * SEQ * DMODEL;

  char* w = (char*)d_ws;
  const size_t MB = 1u << 20;
  unsigned short* Qhi = (unsigned short*)(w + 0 * MB);     // flat [4096][512] bf16, 4MB
  unsigned short* Qlo = (unsigned short*)(w + 4 * MB);     // 4MB
  unsigned short* Khi = (unsigned short*)(w + 8 * MB);     // 4MB, single bf16
  unsigned short* WtHi4 = (unsigned short*)(w + 12 * MB);  // 4 x 512KB = 2MB
  unsigned short* WtLo4 = (unsigned short*)(w + 14 * MB);  // 2MB
  unsigned short* ctx16 = (unsigned short*)(w + 16 * MB);  // 4MB
  unsigned short* Vt = (unsigned short*)(w + 20 * MB);     // 4MB [bh][d][s]
  unsigned int* bits = (unsigned int*)(w + 24 * MB);       // 1 MB

  const size_t WSTRIDE = (size_t)DMODEL * DMODEL;  // 262144 elements per pair

  dim3 blk(256);
  pack_mask_kernel<<<dim3(BATCH * SEQ), blk, 0, stream>>>(mask, bits);

  // all four weight splits in one launch (z: 0=Wq 1=Wk 2=Wv 3=Wo)
  wsplit4_kernel<<<dim3(8, 8, 4), blk, 0, stream>>>(Wq, Wk, Wv, Wo, WtHi4, WtLo4);

  // Q, K, V projections in one launch (z selects; V writes Vt directly)
  proj_qkv_kernel<<<dim3(64, 8, 3), blk, 0, stream>>>(
      q, k, v, WtHi4, WtLo4, bq, bk, bv, Qhi, Qlo, Khi, Vt);

  attn_fused_kernel<<<dim3(2048), dim3(1024), 0, stream>>>(Qhi, Qlo, Khi, bits,
                                                           Vt, attn, ctx16);

  proj_out_kernel<<<dim3(64, 8), blk, 0, stream>>>(
      ctx16, WtHi4 + 3 * WSTRIDE, WtLo4 + 3 * WSTRIDE, bo, out);
}

// Round 20
// 250.241 us; speedup vs baseline: 1.3998x; 1.0031x over previous
//
#include <hip/hip_runtime.h>
#include <math.h>

#define HEADS 8
#define DK 64
#define DMODEL 512
#define BATCH 2
#define SEQ 2048
#define BH (BATCH * HEADS)

using f32x4 = __attribute__((ext_vector_type(4))) float;
using s16x8 = __attribute__((ext_vector_type(8))) short;
using fp16x2 = __attribute__((ext_vector_type(2))) __fp16;  // cvt_pkrtz's type

union FragU {
  uint4 u;
  s16x8 s;
  unsigned short us[8];
};
union PkU {
  fp16x2 h;
  unsigned int u;
};

__device__ __forceinline__ unsigned short f32_to_bf16(float f) {
  unsigned int u = __float_as_uint(f);
  u += 0x7fffu + ((u >> 16) & 1u);
  return (unsigned short)(u >> 16);
}
__device__ __forceinline__ float bf16_to_f32(unsigned short h) {
  return __uint_as_float(((unsigned int)h) << 16);
}

// ---------------------------------------------------------------------------
// mask int32 [B][S][S] -> packed bits [B][S][S/32]. One block per row.
// ---------------------------------------------------------------------------
__global__ __launch_bounds__(256) void pack_mask_kernel(
    const int* __restrict__ mask, unsigned int* __restrict__ bits) {
  const size_t row = blockIdx.x;  // B*S = 4096 rows
  const int wv = threadIdx.x >> 6, lane = threadIdx.x & 63;
  #pragma unroll
  for (int i = 0; i < 8; ++i) {
    const int c = wv * 512 + i * 64 + lane;
    unsigned long long bal = __ballot(mask[row * SEQ + c] != 0);
    if (lane == 0) {
      bits[row * 64 + (c >> 5)] = (unsigned int)bal;
      bits[row * 64 + (c >> 5) + 1] = (unsigned int)(bal >> 32);
    }
  }
}

// ---------------------------------------------------------------------------
// ALL FOUR W[512][512] f32 -> Wt hi/lo bf16 [n][k] in one launch.
// Grid (8,8,4); z selects the weight matrix; pair z lives at z*262144.
// ---------------------------------------------------------------------------
__global__ __launch_bounds__(256) void wsplit4_kernel(
    const float* __restrict__ W0, const float* __restrict__ W1,
    const float* __restrict__ W2, const float* __restrict__ W3,
    unsigned short* __restrict__ WtHi4, unsigned short* __restrict__ WtLo4) {
  __shared__ float t[64][65];
  const int z = blockIdx.z;
  const float* W = (z == 0) ? W0 : (z == 1) ? W1 : (z == 2) ? W2 : W3;
  unsigned short* WtHi = WtHi4 + (size_t)z * (DMODEL * DMODEL);
  unsigned short* WtLo = WtLo4 + (size_t)z * (DMODEL * DMODEL);
  const int k0 = blockIdx.x * 64, n0 = blockIdx.y * 64;
  const int tid = threadIdx.x;
  const int r = tid >> 2, c = (tid & 3) * 16;
  #pragma unroll
  for (int e = 0; e < 4; ++e) {
    f32x4 v = *(const f32x4*)&W[(size_t)(k0 + r) * DMODEL + n0 + c + e * 4];
    #pragma unroll
    for (int j = 0; j < 4; ++j) t[r][c + e * 4 + j] = v[j];
  }
  __syncthreads();
  const int rn = tid >> 2, ck = (tid & 3) * 16;
  #pragma unroll
  for (int half = 0; half < 2; ++half) {
    FragU hi, lo;
    #pragma unroll
    for (int e = 0; e < 8; ++e) {
      float x = t[ck + half * 8 + e][rn];
      unsigned short h = f32_to_bf16(x);
      hi.us[e] = h;
      lo.us[e] = f32_to_bf16(x - bf16_to_f32(h));
    }
    const size_t o = (size_t)(n0 + rn) * DMODEL + k0 + ck + half * 8;
    *(uint4*)&WtHi[o] = hi.u;
    *(uint4*)&WtLo[o] = lo.u;
  }
}

// ---------------------------------------------------------------------------
// Fused Q/K/V projection: one launch, grid (64,8,3). z=0: Q -> bf16 hi/lo
// flat; z=1: K -> bf16 flat; z=2: V -> Vt[bh][d][s] (transposed epilogue).
// Main MFMA loop identical across z (3 MFMAs: ah*bh, ah*bl, al*bh).
// ---------------------------------------------------------------------------
__global__ __launch_bounds__(256) void proj_qkv_kernel(
    const float* __restrict__ Xq, const float* __restrict__ Xk,
    const float* __restrict__ Xv, const unsigned short* __restrict__ WtHi4,
    const unsigned short* __restrict__ WtLo4, const float* __restrict__ bq,
    const float* __restrict__ bk, const float* __restrict__ bv,
    unsigned short* __restrict__ Qhi, unsigned short* __restrict__ Qlo,
    unsigned short* __restrict__ Khi, unsigned short* __restrict__ Vt) {
  __shared__ unsigned short BsHi[64][72];
  __shared__ unsigned short BsLo[64][72];
  const int z = blockIdx.z;
  const float* X = (z == 0) ? Xq : (z == 1) ? Xk : Xv;
  const float* bias = (z == 0) ? bq : (z == 1) ? bk : bv;
  const unsigned short* WtHi = WtHi4 + (size_t)z * (DMODEL * DMODEL);
  const unsigned short* WtLo = WtLo4 + (size_t)z * (DMODEL * DMODEL);

  const int tid = threadIdx.x, wv = tid >> 6, lane = tid & 63;
  const int lr = lane & 15, lg = lane >> 4;
  const int m0 = blockIdx.x * 64;
  const int mw = m0 + wv * 16;
  const int n0 = blockIdx.y * 64;

  f32x4 acc[4] = {};
  for (int k0 = 0; k0 < 512; k0 += 64) {
    FragU ah[2], al[2];
    #pragma unroll
    for (int dc = 0; dc < 2; ++dc) {
      const size_t xi = (size_t)(mw + lr) * DMODEL + k0 + dc * 32 + lg * 8;
      f32x4 x0 = *(const f32x4*)&X[xi];
      f32x4 x1 = *(const f32x4*)&X[xi + 4];
      #pragma unroll
      for (int t = 0; t < 4; ++t) {
        unsigned short h0 = f32_to_bf16(x0[t]);
        unsigned short h1 = f32_to_bf16(x1[t]);
        ah[dc].us[t] = h0;
        ah[dc].us[4 + t] = h1;
        al[dc].us[t] = f32_to_bf16(x0[t] - bf16_to_f32(h0));
        al[dc].us[4 + t] = f32_to_bf16(x1[t] - bf16_to_f32(h1));
      }
    }
    __syncthreads();
    #pragma unroll
    for (int e = 0; e < 2; ++e) {
      const int rr = (tid >> 3) + e * 32;
      const int cc = (tid & 7) * 8;
      *(uint4*)&BsHi[rr][cc] =
          *(const uint4*)&WtHi[(size_t)(n0 + rr) * DMODEL + k0 + cc];
      *(uint4*)&BsLo[rr][cc] =
          *(const uint4*)&WtLo[(size_t)(n0 + rr) * DMODEL + k0 + cc];
    }
    __syncthreads();
    #pragma unroll
    for (int jt = 0; jt < 4; ++jt) {
      #pragma unroll
      for (int dc = 0; dc < 2; ++dc) {
        FragU bh, bl;
        bh.u = *(const uint4*)&BsHi[jt * 16 + lr][dc * 32 + lg * 8];
        bl.u = *(const uint4*)&BsLo[jt * 16 + lr][dc * 32 + lg * 8];
        acc[jt] = __builtin_amdgcn_mfma_f32_16x16x32_bf16(ah[dc].s, bh.s, acc[jt], 0, 0, 0);
        acc[jt] = __builtin_amdgcn_mfma_f32_16x16x32_bf16(ah[dc].s, bl.s, acc[jt], 0, 0, 0);
        acc[jt] = __builtin_amdgcn_mfma_f32_16x16x32_bf16(al[dc].s, bh.s, acc[jt], 0, 0, 0);
      }
    }
  }

  __syncthreads();  // reuse Bs as output staging
  #pragma unroll
  for (int jt = 0; jt < 4; ++jt) {
    const int n = jt * 16 + lr;
    const float bi = bias[n0 + n];
    #pragma unroll
    for (int r = 0; r < 4; ++r) {
      const float v = acc[jt][r] + bi;
      const int row = wv * 16 + lg * 4 + r;
      unsigned short hi = f32_to_bf16(v);
      BsHi[row][n] = hi;
      if (z == 0) BsLo[row][n] = f32_to_bf16(v - bf16_to_f32(hi));
    }
  }
  __syncthreads();
  if (z == 2) {
    // transposed write: Vt[(b*8+h)*64 + d][s0 .. s0+63] (vtrans pattern)
    const int b2 = m0 >> 11, s0 = m0 & 2047, hh = n0 >> 6;
    const int d = tid >> 2, sc = (tid & 3) * 16;
    #pragma unroll
    for (int e = 0; e < 16; ++e)
      Vt[((size_t)(b2 * HEADS + hh) * DK + d) * SEQ + s0 + sc + e] =
          BsHi[sc + e][d];
  } else {
    unsigned short* Yhi = (z == 0) ? Qhi : Khi;
    #pragma unroll
    for (int p = 0; p < 2; ++p) {
      const int row = (tid >> 3) + p * 32;
      const int ch = (tid & 7) * 8;
      const size_t o = (size_t)(m0 + row) * DMODEL + n0 + ch;
      *(uint4*)&Yhi[o] = *(uint4*)&BsHi[row][ch];
      if (z == 0) *(uint4*)&Qlo[o] = *(uint4*)&BsLo[row][ch];
    }
  }
}

// ---------------------------------------------------------------------------
// Output projection (MODE 3 of old proj): X = ctx bf16, Y = out f32.
// ---------------------------------------------------------------------------
__global__ __launch_bounds__(256) void proj_out_kernel(
    const unsigned short* __restrict__ X16, const unsigned short* __restrict__ WtHi,
    const unsigned short* __restrict__ WtLo, const float* __restrict__ bias,
    float* __restrict__ Yf) {
  __shared__ unsigned short BsHi[64][72];
  __shared__ unsigned short BsLo[64][72];
  const int tid = threadIdx.x, wv = tid >> 6, lane = tid & 63;
  const int lr = lane & 15, lg = lane >> 4;
  const int m0 = blockIdx.x * 64;
  const int mw = m0 + wv * 16;
  const int n0 = blockIdx.y * 64;

  f32x4 acc[4] = {};
  for (int k0 = 0; k0 < 512; k0 += 64) {
    FragU ah[2];
    #pragma unroll
    for (int dc = 0; dc < 2; ++dc) {
      const size_t xi = (size_t)(mw + lr) * DMODEL + k0 + dc * 32 + lg * 8;
      ah[dc].u = *(const uint4*)&X16[xi];
    }
    __syncthreads();
    #pragma unroll
    for (int e = 0; e < 2; ++e) {
      const int rr = (tid >> 3) + e * 32;
      const int cc = (tid & 7) * 8;
      *(uint4*)&BsHi[rr][cc] =
          *(const uint4*)&WtHi[(size_t)(n0 + rr) * DMODEL + k0 + cc];
      *(uint4*)&BsLo[rr][cc] =
          *(const uint4*)&WtLo[(size_t)(n0 + rr) * DMODEL + k0 + cc];
    }
    __syncthreads();
    #pragma unroll
    for (int jt = 0; jt < 4; ++jt) {
      #pragma unroll
      for (int dc = 0; dc < 2; ++dc) {
        FragU bh, bl;
        bh.u = *(const uint4*)&BsHi[jt * 16 + lr][dc * 32 + lg * 8];
        bl.u = *(const uint4*)&BsLo[jt * 16 + lr][dc * 32 + lg * 8];
        acc[jt] = __builtin_amdgcn_mfma_f32_16x16x32_bf16(ah[dc].s, bh.s, acc[jt], 0, 0, 0);
        acc[jt] = __builtin_amdgcn_mfma_f32_16x16x32_bf16(ah[dc].s, bl.s, acc[jt], 0, 0, 0);
      }
    }
  }
  #pragma unroll
  for (int jt = 0; jt < 4; ++jt) {
    const int n = n0 + jt * 16 + lr;
    const float bi = bias[n];
    #pragma unroll
    for (int r = 0; r < 4; ++r)
      Yf[(size_t)(mw + lg * 4 + r) * DMODEL + n] = acc[jt][r] + bi;
  }
}

// ---------------------------------------------------------------------------
// ONE-PASS fused attention (R13 config + uint4 bits preload; plain p-stores —
// nt-store variant REGRESSED in R18: +74MB partial-line write traffic).
// 1024 thr / 16 waves, 16 q-rows, 128 cols/wave; no-max softmax; e as f16.
// MFMA maps (verified): A[lr][lg*8+j]; B[lg*8+j][lr]; D[lg*4+r][lr].
// ---------------------------------------------------------------------------
__global__ __launch_bounds__(1024) void attn_fused_kernel(
    const unsigned short* __restrict__ Qhi, const unsigned short* __restrict__ Qlo,
    const unsigned short* __restrict__ Khi, const unsigned int* __restrict__ bits,
    const unsigned short* __restrict__ Vt, float* __restrict__ attn,
    unsigned short* __restrict__ ctx16) {
  __shared__ unsigned short pbuf[16][16 * 76];  // 38912 B (also ctx reduce buf)
  __shared__ float smred[16][16];               // 1 KB (l partials)
  const int id = blockIdx.x;                    // 2048 blocks, XCD-swizzled
  const int xcd = id & 7, slot = id >> 3;       // slot 0..255
  const int bh = xcd + 8 * (slot & 1);
  const int qt = slot >> 1;                     // 0..127
  const int b = bh >> 3, h = bh & 7;
  const int tid = threadIdx.x, wv = tid >> 6, lane = tid & 63;
  const int lr = lane & 15, lg = lane >> 4;
  const int q0 = qt * 16;
  const int kw = wv * 128;  // wave's k-column base

  // Q frags (A layout: q-row = q0 + lr), hi+lo
  FragU qh[2], ql[2];
  #pragma unroll
  for (int dc = 0; dc < 2; ++dc) {
    const size_t qi = (size_t)(b * SEQ + q0 + lr) * DMODEL + h * DK + dc * 32 + lg * 8;
    qh[dc].u = *(const uint4*)&Qhi[qi];
    ql[dc].u = *(const uint4*)&Qlo[qi];
  }
  // mask words for this wave's 128 cols x 4 rows: one uint4 per row
  uint4 mw4[4];
  #pragma unroll
  for (int r = 0; r < 4; ++r) {
    const int q = q0 + lg * 4 + r;
    mw4[r] = *(const uint4*)&bits[((size_t)b * SEQ + q) * 64 + (kw >> 5)];
  }

  // ---- phase 1: e = exp(s/8) (masked -> 0) -> f16 pairs; l accumulates ----
  const float C = 0.125f * 1.44269504089f;  // fold scale into exp2
  PkU epk[8][2];
  float ls[4] = {0.f, 0.f, 0.f, 0.f};
  #pragma unroll
  for (int t = 0; t < 8; ++t) {
    FragU kh[2];
    #pragma unroll
    for (int dc = 0; dc < 2; ++dc) {
      const size_t kidx =
          (size_t)(b * SEQ + kw + t * 16 + lr) * DMODEL + h * DK + dc * 32 + lg * 8;
      kh[dc].u = *(const uint4*)&Khi[kidx];
    }
    f32x4 sa = {};
    #pragma unroll
    for (int dc = 0; dc < 2; ++dc) {
      sa = __builtin_amdgcn_mfma_f32_16x16x32_bf16(qh[dc].s, kh[dc].s, sa, 0, 0, 0);
      sa = __builtin_amdgcn_mfma_f32_16x16x32_bf16(ql[dc].s, kh[dc].s, sa, 0, 0, 0);
    }
    float ev[4];
    #pragma unroll
    for (int r = 0; r < 4; ++r) {
      const unsigned int w =
          (t >> 1) == 0 ? mw4[r].x : (t >> 1) == 1 ? mw4[r].y
          : (t >> 1) == 2 ? mw4[r].z : mw4[r].w;
      const bool keep = (w >> (((t & 1) << 4) + lr)) & 1;
      const float e = keep ? exp2f(sa[r] * C) : 0.0f;
      ev[r] = e;
      ls[r] += e;
    }
    epk[t][0].h = __builtin_amdgcn_cvt_pkrtz(ev[0], ev[1]);
    epk[t][1].h = __builtin_amdgcn_cvt_pkrtz(ev[2], ev[3]);
  }

  // ---- l: shfl reduce over the 16-lane lr group, then cross-wave via LDS ----
  #pragma unroll
  for (int r = 0; r < 4; ++r) {
    #pragma unroll
    for (int off = 1; off < 16; off <<= 1) ls[r] += __shfl_xor(ls[r], off);
    if (lr == 0) smred[wv][lg * 4 + r] = ls[r];
  }
  __syncthreads();
  float il[4];
  #pragma unroll
  for (int r = 0; r < 4; ++r) {
    float l = 0.f;
    #pragma unroll
    for (int w2 = 0; w2 < 16; ++w2) l += smred[w2][lg * 4 + r];
    il[r] = 1.0f / l;
  }

  // ---- phase 2: p = e*il -> attn store + pbuf -> PV MFMA, per 64-col chunk --
  unsigned short* pb = pbuf[wv];
  f32x4 acc[4] = {};
  #pragma unroll
  for (int c = 0; c < 2; ++c) {
    #pragma unroll
    for (int tt = 0; tt < 4; ++tt) {
      const int t = c * 4 + tt;
      float pv4[4];
      pv4[0] = (float)epk[t][0].h.x * il[0];
      pv4[1] = (float)epk[t][0].h.y * il[1];
      pv4[2] = (float)epk[t][1].h.x * il[2];
      pv4[3] = (float)epk[t][1].h.y * il[3];
      #pragma unroll
      for (int r = 0; r < 4; ++r) {
        const int q = q0 + lg * 4 + r;
        attn[((size_t)bh * SEQ + q) * SEQ + kw + t * 16 + lr] = pv4[r];
        pb[(lg * 4 + r) * 76 + tt * 16 + lr] = f32_to_bf16(pv4[r]);
      }
    }
    #pragma unroll
    for (int dc2 = 0; dc2 < 2; ++dc2) {
      FragU pa;
      pa.u = *(const uint4*)&pb[lr * 76 + dc2 * 32 + lg * 8];
      #pragma unroll
      for (int dt = 0; dt < 4; ++dt) {
        FragU bv;
        bv.u = *(const uint4*)&Vt[((size_t)bh * DK + dt * 16 + lr) * SEQ + kw +
                                  c * 64 + dc2 * 32 + lg * 8];
        acc[dt] = __builtin_amdgcn_mfma_f32_16x16x32_bf16(pa.s, bv.s, acc[dt], 0, 0, 0);
      }
    }
  }

  // ---- 16-way ctx tree-reduce through pbuf (max 32 KB in flight) ----
  float* red = (float*)&pbuf[0][0];
  #pragma unroll 1
  for (int ofs = 8; ofs > 0; ofs >>= 1) {
    __syncthreads();
    if (wv >= ofs && wv < 2 * ofs) {
      float* dst = red + (size_t)(wv - ofs) * 1024;
      #pragma unroll
      for (int dt = 0; dt < 4; ++dt) *(f32x4*)&dst[dt * 256 + lane * 4] = acc[dt];
    }
    __syncthreads();
    if (wv < ofs) {
      const float* src = red + (size_t)wv * 1024;
      #pragma unroll
      for (int dt = 0; dt < 4; ++dt) acc[dt] += *(const f32x4*)&src[dt * 256 + lane * 4];
    }
  }
  if (wv == 0) {
    #pragma unroll
    for (int dt = 0; dt < 4; ++dt)
      #pragma unroll
      for (int r = 0; r < 4; ++r) {
        const int q = q0 + lg * 4 + r;
        ctx16[(size_t)(b * SEQ + q) * DMODEL + h * DK + dt * 16 + lr] =
            f32_to_bf16(acc[dt][r]);
      }
  }
}

// ---------------------------------------------------------------------------
extern "C" void kernel_launch(void* const* d_in, const int* in_sizes, int n_in,
                              void* d_out, int out_size, void* d_ws,
                              size_t ws_size, hipStream_t stream) {
  const float* q = (const float*)d_in[0];
  const float* k = (const float*)d_in[1];
  const float* v = (const float*)d_in[2];
  const int* mask = (const int*)d_in[3];
  const float* Wq = (const float*)d_in[4];
  const float* bq = (const float*)d_in[5];
  const float* Wk = (const float*)d_in[6];
  const float* bk = (const float*)d_in[7];
  const float* Wv = (const float*)d_in[8];
  const float* bv = (const float*)d_in[9];
  const float* Wo = (const float*)d_in[10];
  const float* bo = (const float*)d_in[11];

  float* out = (float*)d_out;
  float* attn = out + (size_t)BATCH * SEQ * DMODEL;

  char* w = (char*)d_ws;
  const size_t MB = 1u << 20;
  unsigned short* Qhi = (unsigned short*)(w + 0 * MB);     // flat [4096][512] bf16, 4MB
  unsigned short* Qlo = (unsigned short*)(w + 4 * MB);     // 4MB
  unsigned short* Khi = (unsigned short*)(w + 8 * MB);     // 4MB, single bf16
  unsigned short* WtHi4 = (unsigned short*)(w + 12 * MB);  // 4 x 512KB = 2MB
  unsigned short* WtLo4 = (unsigned short*)(w + 14 * MB);  // 2MB
  unsigned short* ctx16 = (unsigned short*)(w + 16 * MB);  // 4MB
  unsigned short* Vt = (unsigned short*)(w + 20 * MB);     // 4MB [bh][d][s]
  unsigned int* bits = (unsigned int*)(w + 24 * MB);       // 1 MB

  const size_t WSTRIDE = (size_t)DMODEL * DMODEL;  // 262144 elements per pair

  dim3 blk(256);
  pack_mask_kernel<<<dim3(BATCH * SEQ), blk, 0, stream>>>(mask, bits);

  // all four weight splits in one launch (z: 0=Wq 1=Wk 2=Wv 3=Wo)
  wsplit4_kernel<<<dim3(8, 8, 4), blk, 0, stream>>>(Wq, Wk, Wv, Wo, WtHi4, WtLo4);

  // Q, K, V projections in one launch (z selects; V writes Vt directly)
  proj_qkv_kernel<<<dim3(64, 8, 3), blk, 0, stream>>>(
      q, k, v, WtHi4, WtLo4, bq, bk, bv, Qhi, Qlo, Khi, Vt);

  attn_fused_kernel<<<dim3(2048), dim3(1024), 0, stream>>>(Qhi, Qlo, Khi, bits,
                                                           Vt, attn, ctx16);

  proj_out_kernel<<<dim3(64, 8), blk, 0, stream>>>(
      ctx16, WtHi4 + 3 * WSTRIDE, WtLo4 + 3 * WSTRIDE, bo, out);
}

// Round 21
// 239.016 us; speedup vs baseline: 1.4656x; 1.0470x over previous
//
#include <hip/hip_runtime.h>
#include <math.h>

#define HEADS 8
#define DK 64
#define DMODEL 512
#define BATCH 2
#define SEQ 2048
#define BH (BATCH * HEADS)

using f32x4 = __attribute__((ext_vector_type(4))) float;
using s16x8 = __attribute__((ext_vector_type(8))) short;
using fp16x2 = __attribute__((ext_vector_type(2))) __fp16;  // cvt_pkrtz's type

union FragU {
  uint4 u;
  s16x8 s;
  unsigned short us[8];
};
union PkU {
  fp16x2 h;
  unsigned int u;
};

__device__ __forceinline__ unsigned short f32_to_bf16(float f) {
  unsigned int u = __float_as_uint(f);
  u += 0x7fffu + ((u >> 16) & 1u);
  return (unsigned short)(u >> 16);
}
__device__ __forceinline__ float bf16_to_f32(unsigned short h) {
  return __uint_as_float(((unsigned int)h) << 16);
}

// ---------------------------------------------------------------------------
// ALL FOUR W[512][512] f32 -> Wt hi/lo bf16 [n][k] in one launch.
// Grid (8,8,4); z selects the weight matrix; pair z lives at z*262144.
// ---------------------------------------------------------------------------
__global__ __launch_bounds__(256) void wsplit4_kernel(
    const float* __restrict__ W0, const float* __restrict__ W1,
    const float* __restrict__ W2, const float* __restrict__ W3,
    unsigned short* __restrict__ WtHi4, unsigned short* __restrict__ WtLo4) {
  __shared__ float t[64][65];
  const int z = blockIdx.z;
  const float* W = (z == 0) ? W0 : (z == 1) ? W1 : (z == 2) ? W2 : W3;
  unsigned short* WtHi = WtHi4 + (size_t)z * (DMODEL * DMODEL);
  unsigned short* WtLo = WtLo4 + (size_t)z * (DMODEL * DMODEL);
  const int k0 = blockIdx.x * 64, n0 = blockIdx.y * 64;
  const int tid = threadIdx.x;
  const int r = tid >> 2, c = (tid & 3) * 16;
  #pragma unroll
  for (int e = 0; e < 4; ++e) {
    f32x4 v = *(const f32x4*)&W[(size_t)(k0 + r) * DMODEL + n0 + c + e * 4];
    #pragma unroll
    for (int j = 0; j < 4; ++j) t[r][c + e * 4 + j] = v[j];
  }
  __syncthreads();
  const int rn = tid >> 2, ck = (tid & 3) * 16;
  #pragma unroll
  for (int half = 0; half < 2; ++half) {
    FragU hi, lo;
    #pragma unroll
    for (int e = 0; e < 8; ++e) {
      float x = t[ck + half * 8 + e][rn];
      unsigned short h = f32_to_bf16(x);
      hi.us[e] = h;
      lo.us[e] = f32_to_bf16(x - bf16_to_f32(h));
    }
    const size_t o = (size_t)(n0 + rn) * DMODEL + k0 + ck + half * 8;
    *(uint4*)&WtHi[o] = hi.u;
    *(uint4*)&WtLo[o] = lo.u;
  }
}

// ---------------------------------------------------------------------------
// FUSED FRONT: Q/K/V projections (blocks 0..1535) + mask byte-pack (blocks
// 1536..5631) in ONE launch so the 268MB HBM-bound mask read overlaps the
// MFMA-bound projections on idle CUs. Proj blocks dispatch first.
// Proj: z = id/512; z=0: Q -> bf16 hi/lo flat; z=1: K -> bf16 flat;
//       z=2: V -> Vt[bh][d][s] transposed epilogue.
// Pack: thread packs 8 consecutive cols -> 1 byte (little-endian, layout
//       identical to the old __ballot version; attn reads uint4 unchanged).
// ---------------------------------------------------------------------------
__global__ __launch_bounds__(256) void fused_front_kernel(
    const float* __restrict__ Xq, const float* __restrict__ Xk,
    const float* __restrict__ Xv, const unsigned short* __restrict__ WtHi4,
    const unsigned short* __restrict__ WtLo4, const float* __restrict__ bq,
    const float* __restrict__ bk, const float* __restrict__ bv,
    unsigned short* __restrict__ Qhi, unsigned short* __restrict__ Qlo,
    unsigned short* __restrict__ Khi, unsigned short* __restrict__ Vt,
    const int* __restrict__ mask, unsigned int* __restrict__ bits) {
  __shared__ unsigned short BsHi[64][72];
  __shared__ unsigned short BsLo[64][72];
  const int id = blockIdx.x;
  const int tid = threadIdx.x;

  if (id >= 1536) {
    // ---------------- mask pack path ----------------
    const int row = id - 1536;  // 0..4095 = b*SEQ + s
    const int4* mrow = (const int4*)&mask[(size_t)row * SEQ + tid * 8];
    const int4 a = mrow[0];
    const int4 bb = mrow[1];
    unsigned int byte = 0;
    byte |= (a.x != 0) ? 1u : 0u;
    byte |= (a.y != 0) ? 2u : 0u;
    byte |= (a.z != 0) ? 4u : 0u;
    byte |= (a.w != 0) ? 8u : 0u;
    byte |= (bb.x != 0) ? 16u : 0u;
    byte |= (bb.y != 0) ? 32u : 0u;
    byte |= (bb.z != 0) ? 64u : 0u;
    byte |= (bb.w != 0) ? 128u : 0u;
    ((unsigned char*)bits)[(size_t)row * 256 + tid] = (unsigned char)byte;
    return;
  }

  // ---------------- projection path ----------------
  const int z = id >> 9;          // 0..2
  const int rem = id & 511;
  const int m0 = (rem & 63) * 64;
  const int n0 = (rem >> 6) * 64;
  const float* X = (z == 0) ? Xq : (z == 1) ? Xk : Xv;
  const float* bias = (z == 0) ? bq : (z == 1) ? bk : bv;
  const unsigned short* WtHi = WtHi4 + (size_t)z * (DMODEL * DMODEL);
  const unsigned short* WtLo = WtLo4 + (size_t)z * (DMODEL * DMODEL);

  const int wv = tid >> 6, lane = tid & 63;
  const int lr = lane & 15, lg = lane >> 4;
  const int mw = m0 + wv * 16;

  f32x4 acc[4] = {};
  for (int k0 = 0; k0 < 512; k0 += 64) {
    FragU ah[2], al[2];
    #pragma unroll
    for (int dc = 0; dc < 2; ++dc) {
      const size_t xi = (size_t)(mw + lr) * DMODEL + k0 + dc * 32 + lg * 8;
      f32x4 x0 = *(const f32x4*)&X[xi];
      f32x4 x1 = *(const f32x4*)&X[xi + 4];
      #pragma unroll
      for (int t = 0; t < 4; ++t) {
        unsigned short h0 = f32_to_bf16(x0[t]);
        unsigned short h1 = f32_to_bf16(x1[t]);
        ah[dc].us[t] = h0;
        ah[dc].us[4 + t] = h1;
        al[dc].us[t] = f32_to_bf16(x0[t] - bf16_to_f32(h0));
        al[dc].us[4 + t] = f32_to_bf16(x1[t] - bf16_to_f32(h1));
      }
    }
    __syncthreads();
    #pragma unroll
    for (int e = 0; e < 2; ++e) {
      const int rr = (tid >> 3) + e * 32;
      const int cc = (tid & 7) * 8;
      *(uint4*)&BsHi[rr][cc] =
          *(const uint4*)&WtHi[(size_t)(n0 + rr) * DMODEL + k0 + cc];
      *(uint4*)&BsLo[rr][cc] =
          *(const uint4*)&WtLo[(size_t)(n0 + rr) * DMODEL + k0 + cc];
    }
    __syncthreads();
    #pragma unroll
    for (int jt = 0; jt < 4; ++jt) {
      #pragma unroll
      for (int dc = 0; dc < 2; ++dc) {
        FragU bh, bl;
        bh.u = *(const uint4*)&BsHi[jt * 16 + lr][dc * 32 + lg * 8];
        bl.u = *(const uint4*)&BsLo[jt * 16 + lr][dc * 32 + lg * 8];
        acc[jt] = __builtin_amdgcn_mfma_f32_16x16x32_bf16(ah[dc].s, bh.s, acc[jt], 0, 0, 0);
        acc[jt] = __builtin_amdgcn_mfma_f32_16x16x32_bf16(ah[dc].s, bl.s, acc[jt], 0, 0, 0);
        acc[jt] = __builtin_amdgcn_mfma_f32_16x16x32_bf16(al[dc].s, bh.s, acc[jt], 0, 0, 0);
      }
    }
  }

  __syncthreads();  // reuse Bs as output staging
  #pragma unroll
  for (int jt = 0; jt < 4; ++jt) {
    const int n = jt * 16 + lr;
    const float bi = bias[n0 + n];
    #pragma unroll
    for (int r = 0; r < 4; ++r) {
      const float v = acc[jt][r] + bi;
      const int row = wv * 16 + lg * 4 + r;
      unsigned short hi = f32_to_bf16(v);
      BsHi[row][n] = hi;
      if (z == 0) BsLo[row][n] = f32_to_bf16(v - bf16_to_f32(hi));
    }
  }
  __syncthreads();
  if (z == 2) {
    // transposed write: Vt[(b*8+h)*64 + d][s0 .. s0+63] (vtrans pattern)
    const int b2 = m0 >> 11, s0 = m0 & 2047, hh = n0 >> 6;
    const int d = tid >> 2, sc = (tid & 3) * 16;
    #pragma unroll
    for (int e = 0; e < 16; ++e)
      Vt[((size_t)(b2 * HEADS + hh) * DK + d) * SEQ + s0 + sc + e] =
          BsHi[sc + e][d];
  } else {
    unsigned short* Yhi = (z == 0) ? Qhi : Khi;
    #pragma unroll
    for (int p = 0; p < 2; ++p) {
      const int row = (tid >> 3) + p * 32;
      const int ch = (tid & 7) * 8;
      const size_t o = (size_t)(m0 + row) * DMODEL + n0 + ch;
      *(uint4*)&Yhi[o] = *(uint4*)&BsHi[row][ch];
      if (z == 0) *(uint4*)&Qlo[o] = *(uint4*)&BsLo[row][ch];
    }
  }
}

// ---------------------------------------------------------------------------
// Output projection: X = ctx bf16, Y = out f32.
// ---------------------------------------------------------------------------
__global__ __launch_bounds__(256) void proj_out_kernel(
    const unsigned short* __restrict__ X16, const unsigned short* __restrict__ WtHi,
    const unsigned short* __restrict__ WtLo, const float* __restrict__ bias,
    float* __restrict__ Yf) {
  __shared__ unsigned short BsHi[64][72];
  __shared__ unsigned short BsLo[64][72];
  const int tid = threadIdx.x, wv = tid >> 6, lane = tid & 63;
  const int lr = lane & 15, lg = lane >> 4;
  const int m0 = blockIdx.x * 64;
  const int mw = m0 + wv * 16;
  const int n0 = blockIdx.y * 64;

  f32x4 acc[4] = {};
  for (int k0 = 0; k0 < 512; k0 += 64) {
    FragU ah[2];
    #pragma unroll
    for (int dc = 0; dc < 2; ++dc) {
      const size_t xi = (size_t)(mw + lr) * DMODEL + k0 + dc * 32 + lg * 8;
      ah[dc].u = *(const uint4*)&X16[xi];
    }
    __syncthreads();
    #pragma unroll
    for (int e = 0; e < 2; ++e) {
      const int rr = (tid >> 3) + e * 32;
      const int cc = (tid & 7) * 8;
      *(uint4*)&BsHi[rr][cc] =
          *(const uint4*)&WtHi[(size_t)(n0 + rr) * DMODEL + k0 + cc];
      *(uint4*)&BsLo[rr][cc] =
          *(const uint4*)&WtLo[(size_t)(n0 + rr) * DMODEL + k0 + cc];
    }
    __syncthreads();
    #pragma unroll
    for (int jt = 0; jt < 4; ++jt) {
      #pragma unroll
      for (int dc = 0; dc < 2; ++dc) {
        FragU bh, bl;
        bh.u = *(const uint4*)&BsHi[jt * 16 + lr][dc * 32 + lg * 8];
        bl.u = *(const uint4*)&BsLo[jt * 16 + lr][dc * 32 + lg * 8];
        acc[jt] = __builtin_amdgcn_mfma_f32_16x16x32_bf16(ah[dc].s, bh.s, acc[jt], 0, 0, 0);
        acc[jt] = __builtin_amdgcn_mfma_f32_16x16x32_bf16(ah[dc].s, bl.s, acc[jt], 0, 0, 0);
      }
    }
  }
  #pragma unroll
  for (int jt = 0; jt < 4; ++jt) {
    const int n = n0 + jt * 16 + lr;
    const float bi = bias[n];
    #pragma unroll
    for (int r = 0; r < 4; ++r)
      Yf[(size_t)(mw + lg * 4 + r) * DMODEL + n] = acc[jt][r] + bi;
  }
}

// ---------------------------------------------------------------------------
// ONE-PASS fused attention (R13/R20 config — converged at ~188us across 7
// variants; plain p-stores, uint4 bits preload).
// 1024 thr / 16 waves, 16 q-rows, 128 cols/wave; no-max softmax; e as f16.
// MFMA maps (verified): A[lr][lg*8+j]; B[lg*8+j][lr]; D[lg*4+r][lr].
// ---------------------------------------------------------------------------
__global__ __launch_bounds__(1024) void attn_fused_kernel(
    const unsigned short* __restrict__ Qhi, const unsigned short* __restrict__ Qlo,
    const unsigned short* __restrict__ Khi, const unsigned int* __restrict__ bits,
    const unsigned short* __restrict__ Vt, float* __restrict__ attn,
    unsigned short* __restrict__ ctx16) {
  __shared__ unsigned short pbuf[16][16 * 76];  // 38912 B (also ctx reduce buf)
  __shared__ float smred[16][16];               // 1 KB (l partials)
  const int id = blockIdx.x;                    // 2048 blocks, XCD-swizzled
  const int xcd = id & 7, slot = id >> 3;       // slot 0..255
  const int bh = xcd + 8 * (slot & 1);
  const int qt = slot >> 1;                     // 0..127
  const int b = bh >> 3, h = bh & 7;
  const int tid = threadIdx.x, wv = tid >> 6, lane = tid & 63;
  const int lr = lane & 15, lg = lane >> 4;
  const int q0 = qt * 16;
  const int kw = wv * 128;  // wave's k-column base

  // Q frags (A layout: q-row = q0 + lr), hi+lo
  FragU qh[2], ql[2];
  #pragma unroll
  for (int dc = 0; dc < 2; ++dc) {
    const size_t qi = (size_t)(b * SEQ + q0 + lr) * DMODEL + h * DK + dc * 32 + lg * 8;
    qh[dc].u = *(const uint4*)&Qhi[qi];
    ql[dc].u = *(const uint4*)&Qlo[qi];
  }
  // mask words for this wave's 128 cols x 4 rows: one uint4 per row
  uint4 mw4[4];
  #pragma unroll
  for (int r = 0; r < 4; ++r) {
    const int q = q0 + lg * 4 + r;
    mw4[r] = *(const uint4*)&bits[((size_t)b * SEQ + q) * 64 + (kw >> 5)];
  }

  // ---- phase 1: e = exp(s/8) (masked -> 0) -> f16 pairs; l accumulates ----
  const float C = 0.125f * 1.44269504089f;  // fold scale into exp2
  PkU epk[8][2];
  float ls[4] = {0.f, 0.f, 0.f, 0.f};
  #pragma unroll
  for (int t = 0; t < 8; ++t) {
    FragU kh[2];
    #pragma unroll
    for (int dc = 0; dc < 2; ++dc) {
      const size_t kidx =
          (size_t)(b * SEQ + kw + t * 16 + lr) * DMODEL + h * DK + dc * 32 + lg * 8;
      kh[dc].u = *(const uint4*)&Khi[kidx];
    }
    f32x4 sa = {};
    #pragma unroll
    for (int dc = 0; dc < 2; ++dc) {
      sa = __builtin_amdgcn_mfma_f32_16x16x32_bf16(qh[dc].s, kh[dc].s, sa, 0, 0, 0);
      sa = __builtin_amdgcn_mfma_f32_16x16x32_bf16(ql[dc].s, kh[dc].s, sa, 0, 0, 0);
    }
    float ev[4];
    #pragma unroll
    for (int r = 0; r < 4; ++r) {
      const unsigned int w =
          (t >> 1) == 0 ? mw4[r].x : (t >> 1) == 1 ? mw4[r].y
          : (t >> 1) == 2 ? mw4[r].z : mw4[r].w;
      const bool keep = (w >> (((t & 1) << 4) + lr)) & 1;
      const float e = keep ? exp2f(sa[r] * C) : 0.0f;
      ev[r] = e;
      ls[r] += e;
    }
    epk[t][0].h = __builtin_amdgcn_cvt_pkrtz(ev[0], ev[1]);
    epk[t][1].h = __builtin_amdgcn_cvt_pkrtz(ev[2], ev[3]);
  }

  // ---- l: shfl reduce over the 16-lane lr group, then cross-wave via LDS ----
  #pragma unroll
  for (int r = 0; r < 4; ++r) {
    #pragma unroll
    for (int off = 1; off < 16; off <<= 1) ls[r] += __shfl_xor(ls[r], off);
    if (lr == 0) smred[wv][lg * 4 + r] = ls[r];
  }
  __syncthreads();
  float il[4];
  #pragma unroll
  for (int r = 0; r < 4; ++r) {
    float l = 0.f;
    #pragma unroll
    for (int w2 = 0; w2 < 16; ++w2) l += smred[w2][lg * 4 + r];
    il[r] = 1.0f / l;
  }

  // ---- phase 2: p = e*il -> attn store + pbuf -> PV MFMA, per 64-col chunk --
  unsigned short* pb = pbuf[wv];
  f32x4 acc[4] = {};
  #pragma unroll
  for (int c = 0; c < 2; ++c) {
    #pragma unroll
    for (int tt = 0; tt < 4; ++tt) {
      const int t = c * 4 + tt;
      float pv4[4];
      pv4[0] = (float)epk[t][0].h.x * il[0];
      pv4[1] = (float)epk[t][0].h.y * il[1];
      pv4[2] = (float)epk[t][1].h.x * il[2];
      pv4[3] = (float)epk[t][1].h.y * il[3];
      #pragma unroll
      for (int r = 0; r < 4; ++r) {
        const int q = q0 + lg * 4 + r;
        attn[((size_t)bh * SEQ + q) * SEQ + kw + t * 16 + lr] = pv4[r];
        pb[(lg * 4 + r) * 76 + tt * 16 + lr] = f32_to_bf16(pv4[r]);
      }
    }
    #pragma unroll
    for (int dc2 = 0; dc2 < 2; ++dc2) {
      FragU pa;
      pa.u = *(const uint4*)&pb[lr * 76 + dc2 * 32 + lg * 8];
      #pragma unroll
      for (int dt = 0; dt < 4; ++dt) {
        FragU bv;
        bv.u = *(const uint4*)&Vt[((size_t)bh * DK + dt * 16 + lr) * SEQ + kw +
                                  c * 64 + dc2 * 32 + lg * 8];
        acc[dt] = __builtin_amdgcn_mfma_f32_16x16x32_bf16(pa.s, bv.s, acc[dt], 0, 0, 0);
      }
    }
  }

  // ---- 16-way ctx tree-reduce through pbuf (max 32 KB in flight) ----
  float* red = (float*)&pbuf[0][0];
  #pragma unroll 1
  for (int ofs = 8; ofs > 0; ofs >>= 1) {
    __syncthreads();
    if (wv >= ofs && wv < 2 * ofs) {
      float* dst = red + (size_t)(wv - ofs) * 1024;
      #pragma unroll
      for (int dt = 0; dt < 4; ++dt) *(f32x4*)&dst[dt * 256 + lane * 4] = acc[dt];
    }
    __syncthreads();
    if (wv < ofs) {
      const float* src = red + (size_t)wv * 1024;
      #pragma unroll
      for (int dt = 0; dt < 4; ++dt) acc[dt] += *(const f32x4*)&src[dt * 256 + lane * 4];
    }
  }
  if (wv == 0) {
    #pragma unroll
    for (int dt = 0; dt < 4; ++dt)
      #pragma unroll
      for (int r = 0; r < 4; ++r) {
        const int q = q0 + lg * 4 + r;
        ctx16[(size_t)(b * SEQ + q) * DMODEL + h * DK + dt * 16 + lr] =
            f32_to_bf16(acc[dt][r]);
      }
  }
}

// ---------------------------------------------------------------------------
extern "C" void kernel_launch(void* const* d_in, const int* in_sizes, int n_in,
                              void* d_out, int out_size, void* d_ws,
                              size_t ws_size, hipStream_t stream) {
  const float* q = (const float*)d_in[0];
  const float* k = (const float*)d_in[1];
  const float* v = (const float*)d_in[2];
  const int* mask = (const int*)d_in[3];
  const float* Wq = (const float*)d_in[4];
  const float* bq = (const float*)d_in[5];
  const float* Wk = (const float*)d_in[6];
  const float* bk = (const float*)d_in[7];
  const float* Wv = (const float*)d_in[8];
  const float* bv = (const float*)d_in[9];
  const float* Wo = (const float*)d_in[10];
  const float* bo = (const float*)d_in[11];

  float* out = (float*)d_out;
  float* attn = out + (size_t)BATCH * SEQ * DMODEL;

  char* w = (char*)d_ws;
  const size_t MB = 1u << 20;
  unsigned short* Qhi = (unsigned short*)(w + 0 * MB);     // flat [4096][512] bf16, 4MB
  unsigned short* Qlo = (unsigned short*)(w + 4 * MB);     // 4MB
  unsigned short* Khi = (unsigned short*)(w + 8 * MB);     // 4MB, single bf16
  unsigned short* WtHi4 = (unsigned short*)(w + 12 * MB);  // 4 x 512KB = 2MB
  unsigned short* WtLo4 = (unsigned short*)(w + 14 * MB);  // 2MB
  unsigned short* ctx16 = (unsigned short*)(w + 16 * MB);  // 4MB
  unsigned short* Vt = (unsigned short*)(w + 20 * MB);     // 4MB [bh][d][s]
  unsigned int* bits = (unsigned int*)(w + 24 * MB);       // 1 MB

  const size_t WSTRIDE = (size_t)DMODEL * DMODEL;  // 262144 elements per pair

  dim3 blk(256);
  // all four weight splits in one launch (z: 0=Wq 1=Wk 2=Wv 3=Wo)
  wsplit4_kernel<<<dim3(8, 8, 4), blk, 0, stream>>>(Wq, Wk, Wv, Wo, WtHi4, WtLo4);

  // Q/K/V projections + mask pack co-scheduled in one launch:
  // blocks 0..1535 = proj (dispatch first), 1536..5631 = mask rows.
  fused_front_kernel<<<dim3(5632), blk, 0, stream>>>(
      q, k, v, WtHi4, WtLo4, bq, bk, bv, Qhi, Qlo, Khi, Vt, mask, bits);

  attn_fused_kernel<<<dim3(2048), dim3(1024), 0, stream>>>(Qhi, Qlo, Khi, bits,
                                                           Vt, attn, ctx16);

  proj_out_kernel<<<dim3(64, 8), blk, 0, stream>>>(
      ctx16, WtHi4 + 3 * WSTRIDE, WtLo4 + 3 * WSTRIDE, bo, out);
}

// Round 22
// 208.283 us; speedup vs baseline: 1.6818x; 1.1476x over previous
//
#include <hip/hip_runtime.h>
#include <math.h>

#define HEADS 8
#define DK 64
#define DMODEL 512
#define BATCH 2
#define SEQ 2048
#define BH (BATCH * HEADS)

using f32x4 = __attribute__((ext_vector_type(4))) float;
using s16x8 = __attribute__((ext_vector_type(8))) short;
using fp16x2 = __attribute__((ext_vector_type(2))) __fp16;  // cvt_pkrtz's type

union FragU {
  uint4 u;
  s16x8 s;
  unsigned short us[8];
};
union PkU {
  fp16x2 h;
  unsigned int u;
};

__device__ __forceinline__ unsigned short f32_to_bf16(float f) {
  unsigned int u = __float_as_uint(f);
  u += 0x7fffu + ((u >> 16) & 1u);
  return (unsigned short)(u >> 16);
}
__device__ __forceinline__ float bf16_to_f32(unsigned short h) {
  return __uint_as_float(((unsigned int)h) << 16);
}

// ---------------------------------------------------------------------------
// ALL FOUR W[512][512] f32 -> Wt hi/lo bf16 [n][k] in one launch.
// ---------------------------------------------------------------------------
__global__ __launch_bounds__(256) void wsplit4_kernel(
    const float* __restrict__ W0, const float* __restrict__ W1,
    const float* __restrict__ W2, const float* __restrict__ W3,
    unsigned short* __restrict__ WtHi4, unsigned short* __restrict__ WtLo4) {
  __shared__ float t[64][65];
  const int z = blockIdx.z;
  const float* W = (z == 0) ? W0 : (z == 1) ? W1 : (z == 2) ? W2 : W3;
  unsigned short* WtHi = WtHi4 + (size_t)z * (DMODEL * DMODEL);
  unsigned short* WtLo = WtLo4 + (size_t)z * (DMODEL * DMODEL);
  const int k0 = blockIdx.x * 64, n0 = blockIdx.y * 64;
  const int tid = threadIdx.x;
  const int r = tid >> 2, c = (tid & 3) * 16;
  #pragma unroll
  for (int e = 0; e < 4; ++e) {
    f32x4 v = *(const f32x4*)&W[(size_t)(k0 + r) * DMODEL + n0 + c + e * 4];
    #pragma unroll
    for (int j = 0; j < 4; ++j) t[r][c + e * 4 + j] = v[j];
  }
  __syncthreads();
  const int rn = tid >> 2, ck = (tid & 3) * 16;
  #pragma unroll
  for (int half = 0; half < 2; ++half) {
    FragU hi, lo;
    #pragma unroll
    for (int e = 0; e < 8; ++e) {
      float x = t[ck + half * 8 + e][rn];
      unsigned short h = f32_to_bf16(x);
      hi.us[e] = h;
      lo.us[e] = f32_to_bf16(x - bf16_to_f32(h));
    }
    const size_t o = (size_t)(n0 + rn) * DMODEL + k0 + ck + half * 8;
    *(uint4*)&WtHi[o] = hi.u;
    *(uint4*)&WtLo[o] = lo.u;
  }
}

// ---------------------------------------------------------------------------
// FUSED FRONT: Q/K/V projections (blocks 0..1535) + mask byte-pack (rest).
// ---------------------------------------------------------------------------
__global__ __launch_bounds__(256) void fused_front_kernel(
    const float* __restrict__ Xq, const float* __restrict__ Xk,
    const float* __restrict__ Xv, const unsigned short* __restrict__ WtHi4,
    const unsigned short* __restrict__ WtLo4, const float* __restrict__ bq,
    const float* __restrict__ bk, const float* __restrict__ bv,
    unsigned short* __restrict__ Qhi, unsigned short* __restrict__ Qlo,
    unsigned short* __restrict__ Khi, unsigned short* __restrict__ Vt,
    const int* __restrict__ mask, unsigned int* __restrict__ bits) {
  __shared__ unsigned short BsHi[64][72];
  __shared__ unsigned short BsLo[64][72];
  const int id = blockIdx.x;
  const int tid = threadIdx.x;

  if (id >= 1536) {
    const int row = id - 1536;  // 0..4095
    const int4* mrow = (const int4*)&mask[(size_t)row * SEQ + tid * 8];
    const int4 a = mrow[0];
    const int4 bb = mrow[1];
    unsigned int byte = 0;
    byte |= (a.x != 0) ? 1u : 0u;
    byte |= (a.y != 0) ? 2u : 0u;
    byte |= (a.z != 0) ? 4u : 0u;
    byte |= (a.w != 0) ? 8u : 0u;
    byte |= (bb.x != 0) ? 16u : 0u;
    byte |= (bb.y != 0) ? 32u : 0u;
    byte |= (bb.z != 0) ? 64u : 0u;
    byte |= (bb.w != 0) ? 128u : 0u;
    ((unsigned char*)bits)[(size_t)row * 256 + tid] = (unsigned char)byte;
    return;
  }

  const int z = id >> 9;
  const int rem = id & 511;
  const int m0 = (rem & 63) * 64;
  const int n0 = (rem >> 6) * 64;
  const float* X = (z == 0) ? Xq : (z == 1) ? Xk : Xv;
  const float* bias = (z == 0) ? bq : (z == 1) ? bk : bv;
  const unsigned short* WtHi = WtHi4 + (size_t)z * (DMODEL * DMODEL);
  const unsigned short* WtLo = WtLo4 + (size_t)z * (DMODEL * DMODEL);

  const int wv = tid >> 6, lane = tid & 63;
  const int lr = lane & 15, lg = lane >> 4;
  const int mw = m0 + wv * 16;

  f32x4 acc[4] = {};
  for (int k0 = 0; k0 < 512; k0 += 64) {
    FragU ah[2], al[2];
    #pragma unroll
    for (int dc = 0; dc < 2; ++dc) {
      const size_t xi = (size_t)(mw + lr) * DMODEL + k0 + dc * 32 + lg * 8;
      f32x4 x0 = *(const f32x4*)&X[xi];
      f32x4 x1 = *(const f32x4*)&X[xi + 4];
      #pragma unroll
      for (int t = 0; t < 4; ++t) {
        unsigned short h0 = f32_to_bf16(x0[t]);
        unsigned short h1 = f32_to_bf16(x1[t]);
        ah[dc].us[t] = h0;
        ah[dc].us[4 + t] = h1;
        al[dc].us[t] = f32_to_bf16(x0[t] - bf16_to_f32(h0));
        al[dc].us[4 + t] = f32_to_bf16(x1[t] - bf16_to_f32(h1));
      }
    }
    __syncthreads();
    #pragma unroll
    for (int e = 0; e < 2; ++e) {
      const int rr = (tid >> 3) + e * 32;
      const int cc = (tid & 7) * 8;
      *(uint4*)&BsHi[rr][cc] =
          *(const uint4*)&WtHi[(size_t)(n0 + rr) * DMODEL + k0 + cc];
      *(uint4*)&BsLo[rr][cc] =
          *(const uint4*)&WtLo[(size_t)(n0 + rr) * DMODEL + k0 + cc];
    }
    __syncthreads();
    #pragma unroll
    for (int jt = 0; jt < 4; ++jt) {
      #pragma unroll
      for (int dc = 0; dc < 2; ++dc) {
        FragU bh, bl;
        bh.u = *(const uint4*)&BsHi[jt * 16 + lr][dc * 32 + lg * 8];
        bl.u = *(const uint4*)&BsLo[jt * 16 + lr][dc * 32 + lg * 8];
        acc[jt] = __builtin_amdgcn_mfma_f32_16x16x32_bf16(ah[dc].s, bh.s, acc[jt], 0, 0, 0);
        acc[jt] = __builtin_amdgcn_mfma_f32_16x16x32_bf16(ah[dc].s, bl.s, acc[jt], 0, 0, 0);
        acc[jt] = __builtin_amdgcn_mfma_f32_16x16x32_bf16(al[dc].s, bh.s, acc[jt], 0, 0, 0);
      }
    }
  }

  __syncthreads();
  #pragma unroll
  for (int jt = 0; jt < 4; ++jt) {
    const int n = jt * 16 + lr;
    const float bi = bias[n0 + n];
    #pragma unroll
    for (int r = 0; r < 4; ++r) {
      const float v = acc[jt][r] + bi;
      const int row = wv * 16 + lg * 4 + r;
      unsigned short hi = f32_to_bf16(v);
      BsHi[row][n] = hi;
      if (z == 0) BsLo[row][n] = f32_to_bf16(v - bf16_to_f32(hi));
    }
  }
  __syncthreads();
  if (z == 2) {
    const int b2 = m0 >> 11, s0 = m0 & 2047, hh = n0 >> 6;
    const int d = tid >> 2, sc = (tid & 3) * 16;
    #pragma unroll
    for (int e = 0; e < 16; ++e)
      Vt[((size_t)(b2 * HEADS + hh) * DK + d) * SEQ + s0 + sc + e] =
          BsHi[sc + e][d];
  } else {
    unsigned short* Yhi = (z == 0) ? Qhi : Khi;
    #pragma unroll
    for (int p = 0; p < 2; ++p) {
      const int row = (tid >> 3) + p * 32;
      const int ch = (tid & 7) * 8;
      const size_t o = (size_t)(m0 + row) * DMODEL + n0 + ch;
      *(uint4*)&Yhi[o] = *(uint4*)&BsHi[row][ch];
      if (z == 0) *(uint4*)&Qlo[o] = *(uint4*)&BsLo[row][ch];
    }
  }
}

// ---------------------------------------------------------------------------
// Output projection: X = ctx bf16, Y = out f32.
// ---------------------------------------------------------------------------
__global__ __launch_bounds__(256) void proj_out_kernel(
    const unsigned short* __restrict__ X16, const unsigned short* __restrict__ WtHi,
    const unsigned short* __restrict__ WtLo, const float* __restrict__ bias,
    float* __restrict__ Yf) {
  __shared__ unsigned short BsHi[64][72];
  __shared__ unsigned short BsLo[64][72];
  const int tid = threadIdx.x, wv = tid >> 6, lane = tid & 63;
  const int lr = lane & 15, lg = lane >> 4;
  const int m0 = blockIdx.x * 64;
  const int mw = m0 + wv * 16;
  const int n0 = blockIdx.y * 64;

  f32x4 acc[4] = {};
  for (int k0 = 0; k0 < 512; k0 += 64) {
    FragU ah[2];
    #pragma unroll
    for (int dc = 0; dc < 2; ++dc) {
      const size_t xi = (size_t)(mw + lr) * DMODEL + k0 + dc * 32 + lg * 8;
      ah[dc].u = *(const uint4*)&X16[xi];
    }
    __syncthreads();
    #pragma unroll
    for (int e = 0; e < 2; ++e) {
      const int rr = (tid >> 3) + e * 32;
      const int cc = (tid & 7) * 8;
      *(uint4*)&BsHi[rr][cc] =
          *(const uint4*)&WtHi[(size_t)(n0 + rr) * DMODEL + k0 + cc];
      *(uint4*)&BsLo[rr][cc] =
          *(const uint4*)&WtLo[(size_t)(n0 + rr) * DMODEL + k0 + cc];
    }
    __syncthreads();
    #pragma unroll
    for (int jt = 0; jt < 4; ++jt) {
      #pragma unroll
      for (int dc = 0; dc < 2; ++dc) {
        FragU bh, bl;
        bh.u = *(const uint4*)&BsHi[jt * 16 + lr][dc * 32 + lg * 8];
        bl.u = *(const uint4*)&BsLo[jt * 16 + lr][dc * 32 + lg * 8];
        acc[jt] = __builtin_amdgcn_mfma_f32_16x16x32_bf16(ah[dc].s, bh.s, acc[jt], 0, 0, 0);
        acc[jt] = __builtin_amdgcn_mfma_f32_16x16x32_bf16(ah[dc].s, bl.s, acc[jt], 0, 0, 0);
      }
    }
  }
  #pragma unroll
  for (int jt = 0; jt < 4; ++jt) {
    const int n = n0 + jt * 16 + lr;
    const float bi = bias[n];
    #pragma unroll
    for (int r = 0; r < 4; ++r)
      Yf[(size_t)(mw + lg * 4 + r) * DMODEL + n] = acc[jt][r] + bi;
  }
}

// ---------------------------------------------------------------------------
// ONE-PASS fused attention v6: 512 thr / 8 waves (NO 64-VGPR cap), 16 q-rows,
// 256 cols/wave, K loaded in TWO BATCHES of 16 uint4 (2 L2 round-trips
// instead of 16 serial ones — the 1024-thr builds were register-capped at
// 52-64 VGPR and could not pipeline). V frags issued at the top of each
// 64-col chunk so their latency hides under p/pbuf work.
// No-max softmax; e as f16 pairs; pbuf stride 76; 8-way ctx tree-reduce.
// MFMA maps (verified): A[lr][lg*8+j]; B[lg*8+j][lr]; D[lg*4+r][lr].
// ---------------------------------------------------------------------------
__global__ __launch_bounds__(512) void attn_fused_kernel(
    const unsigned short* __restrict__ Qhi, const unsigned short* __restrict__ Qlo,
    const unsigned short* __restrict__ Khi, const unsigned int* __restrict__ bits,
    const unsigned short* __restrict__ Vt, float* __restrict__ attn,
    unsigned short* __restrict__ ctx16) {
  __shared__ unsigned short pbuf[8][16 * 76];  // 19456 B (also ctx reduce buf)
  __shared__ float smred[8][16];               // 512 B (l partials)
  const int id = blockIdx.x;                   // 2048 blocks, XCD-swizzled
  const int xcd = id & 7, slot = id >> 3;      // slot 0..255
  const int bh = xcd + 8 * (slot & 1);
  const int qt = slot >> 1;                    // 0..127
  const int b = bh >> 3, h = bh & 7;
  const int tid = threadIdx.x, wv = tid >> 6, lane = tid & 63;
  const int lr = lane & 15, lg = lane >> 4;
  const int q0 = qt * 16;
  const int kw = wv * 256;  // wave's k-column base (8 waves x 256 = 2048)

  // Q frags (A layout: q-row = q0 + lr), hi+lo
  FragU qh[2], ql[2];
  #pragma unroll
  for (int dc = 0; dc < 2; ++dc) {
    const size_t qi = (size_t)(b * SEQ + q0 + lr) * DMODEL + h * DK + dc * 32 + lg * 8;
    qh[dc].u = *(const uint4*)&Qhi[qi];
    ql[dc].u = *(const uint4*)&Qlo[qi];
  }
  // mask words: 256 cols = 8 words per row -> two uint4 per row
  uint4 mw8[4][2];
  #pragma unroll
  for (int r = 0; r < 4; ++r) {
    const size_t base = ((size_t)b * SEQ + q0 + lg * 4 + r) * 64 + (kw >> 5);
    mw8[r][0] = *(const uint4*)&bits[base];
    mw8[r][1] = *(const uint4*)&bits[base + 4];
  }

  // ---- phase 1: 2 batches of 8 t-steps; K prefetched per batch ----
  const float C = 0.125f * 1.44269504089f;  // fold scale into exp2
  PkU epk[16][2];
  float ls[4] = {0.f, 0.f, 0.f, 0.f};
  #pragma unroll
  for (int g = 0; g < 2; ++g) {
    FragU kh[8][2];  // 16 uint4 = 64 VGPR in flight
    #pragma unroll
    for (int tt = 0; tt < 8; ++tt) {
      const int t = g * 8 + tt;
      #pragma unroll
      for (int dc = 0; dc < 2; ++dc) {
        const size_t kidx =
            (size_t)(b * SEQ + kw + t * 16 + lr) * DMODEL + h * DK + dc * 32 + lg * 8;
        kh[tt][dc].u = *(const uint4*)&Khi[kidx];
      }
    }
    #pragma unroll
    for (int tt = 0; tt < 8; ++tt) {
      const int t = g * 8 + tt;
      f32x4 sa = {};
      #pragma unroll
      for (int dc = 0; dc < 2; ++dc) {
        sa = __builtin_amdgcn_mfma_f32_16x16x32_bf16(qh[dc].s, kh[tt][dc].s, sa, 0, 0, 0);
        sa = __builtin_amdgcn_mfma_f32_16x16x32_bf16(ql[dc].s, kh[tt][dc].s, sa, 0, 0, 0);
      }
      const int wi = t >> 1;  // 0..7, compile-time
      float ev[4];
      #pragma unroll
      for (int r = 0; r < 4; ++r) {
        const uint4 m4 = mw8[r][wi >> 2];
        const unsigned int w =
            (wi & 3) == 0 ? m4.x : (wi & 3) == 1 ? m4.y : (wi & 3) == 2 ? m4.z : m4.w;
        const bool keep = (w >> (((t & 1) << 4) + lr)) & 1;
        const float e = keep ? exp2f(sa[r] * C) : 0.0f;
        ev[r] = e;
        ls[r] += e;
      }
      epk[t][0].h = __builtin_amdgcn_cvt_pkrtz(ev[0], ev[1]);
      epk[t][1].h = __builtin_amdgcn_cvt_pkrtz(ev[2], ev[3]);
    }
  }

  // ---- l: shfl reduce over the 16-lane lr group, then cross-wave via LDS ----
  #pragma unroll
  for (int r = 0; r < 4; ++r) {
    #pragma unroll
    for (int off = 1; off < 16; off <<= 1) ls[r] += __shfl_xor(ls[r], off);
    if (lr == 0) smred[wv][lg * 4 + r] = ls[r];
  }
  __syncthreads();
  float il[4];
  #pragma unroll
  for (int r = 0; r < 4; ++r) {
    float l = 0.f;
    #pragma unroll
    for (int w2 = 0; w2 < 8; ++w2) l += smred[w2][lg * 4 + r];
    il[r] = 1.0f / l;
  }

  // ---- phase 2: per 64-col chunk: V prefetch -> p/attn/pbuf -> PV MFMA ----
  unsigned short* pb = pbuf[wv];
  f32x4 acc[4] = {};
  #pragma unroll
  for (int c = 0; c < 4; ++c) {
    // issue all 8 V loads for this chunk first (latency hides under p work)
    FragU vv[2][4];
    #pragma unroll
    for (int dc2 = 0; dc2 < 2; ++dc2)
      #pragma unroll
      for (int dt = 0; dt < 4; ++dt)
        vv[dc2][dt].u = *(const uint4*)&Vt[((size_t)bh * DK + dt * 16 + lr) * SEQ +
                                           kw + c * 64 + dc2 * 32 + lg * 8];
    #pragma unroll
    for (int tt = 0; tt < 4; ++tt) {
      const int t = c * 4 + tt;
      float pv4[4];
      pv4[0] = (float)epk[t][0].h.x * il[0];
      pv4[1] = (float)epk[t][0].h.y * il[1];
      pv4[2] = (float)epk[t][1].h.x * il[2];
      pv4[3] = (float)epk[t][1].h.y * il[3];
      #pragma unroll
      for (int r = 0; r < 4; ++r) {
        const int q = q0 + lg * 4 + r;
        attn[((size_t)bh * SEQ + q) * SEQ + kw + t * 16 + lr] = pv4[r];
        pb[(lg * 4 + r) * 76 + tt * 16 + lr] = f32_to_bf16(pv4[r]);
      }
    }
    #pragma unroll
    for (int dc2 = 0; dc2 < 2; ++dc2) {
      FragU pa;
      pa.u = *(const uint4*)&pb[lr * 76 + dc2 * 32 + lg * 8];
      #pragma unroll
      for (int dt = 0; dt < 4; ++dt)
        acc[dt] = __builtin_amdgcn_mfma_f32_16x16x32_bf16(pa.s, vv[dc2][dt].s, acc[dt], 0, 0, 0);
    }
  }

  // ---- 8-way ctx tree-reduce through pbuf (16 KB max in flight) ----
  float* red = (float*)&pbuf[0][0];
  #pragma unroll 1
  for (int ofs = 4; ofs > 0; ofs >>= 1) {
    __syncthreads();
    if (wv >= ofs && wv < 2 * ofs) {
      float* dst = red + (size_t)(wv - ofs) * 1024;
      #pragma unroll
      for (int dt = 0; dt < 4; ++dt) *(f32x4*)&dst[dt * 256 + lane * 4] = acc[dt];
    }
    __syncthreads();
    if (wv < ofs) {
      const float* src = red + (size_t)wv * 1024;
      #pragma unroll
      for (int dt = 0; dt < 4; ++dt) acc[dt] += *(const f32x4*)&src[dt * 256 + lane * 4];
    }
  }
  if (wv == 0) {
    #pragma unroll
    for (int dt = 0; dt < 4; ++dt)
      #pragma unroll
      for (int r = 0; r < 4; ++r) {
        const int q = q0 + lg * 4 + r;
        ctx16[(size_t)(b * SEQ + q) * DMODEL + h * DK + dt * 16 + lr] =
            f32_to_bf16(acc[dt][r]);
      }
  }
}

// ---------------------------------------------------------------------------
extern "C" void kernel_launch(void* const* d_in, const int* in_sizes, int n_in,
                              void* d_out, int out_size, void* d_ws,
                              size_t ws_size, hipStream_t stream) {
  const float* q = (const float*)d_in[0];
  const float* k = (const float*)d_in[1];
  const float* v = (const float*)d_in[2];
  const int* mask = (const int*)d_in[3];
  const float* Wq = (const float*)d_in[4];
  const float* bq = (const float*)d_in[5];
  const float* Wk = (const float*)d_in[6];
  const float* bk = (const float*)d_in[7];
  const float* Wv = (const float*)d_in[8];
  const float* bv = (const float*)d_in[9];
  const float* Wo = (const float*)d_in[10];
  const float* bo = (const float*)d_in[11];

  float* out = (float*)d_out;
  float* attn = out + (size_t)BATCH * SEQ * DMODEL;

  char* w = (char*)d_ws;
  const size_t MB = 1u << 20;
  unsigned short* Qhi = (unsigned short*)(w + 0 * MB);     // flat [4096][512] bf16, 4MB
  unsigned short* Qlo = (unsigned short*)(w + 4 * MB);     // 4MB
  unsigned short* Khi = (unsigned short*)(w + 8 * MB);     // 4MB, single bf16
  unsigned short* WtHi4 = (unsigned short*)(w + 12 * MB);  // 4 x 512KB = 2MB
  unsigned short* WtLo4 = (unsigned short*)(w + 14 * MB);  // 2MB
  unsigned short* ctx16 = (unsigned short*)(w + 16 * MB);  // 4MB
  unsigned short* Vt = (unsigned short*)(w + 20 * MB);     // 4MB [bh][d][s]
  unsigned int* bits = (unsigned int*)(w + 24 * MB);       // 1 MB

  const size_t WSTRIDE = (size_t)DMODEL * DMODEL;  // 262144 elements per pair

  dim3 blk(256);
  wsplit4_kernel<<<dim3(8, 8, 4), blk, 0, stream>>>(Wq, Wk, Wv, Wo, WtHi4, WtLo4);

  fused_front_kernel<<<dim3(5632), blk, 0, stream>>>(
      q, k, v, WtHi4, WtLo4, bq, bk, bv, Qhi, Qlo, Khi, Vt, mask, bits);

  attn_fused_kernel<<<dim3(2048), dim3(512), 0, stream>>>(Qhi, Qlo, Khi, bits,
                                                          Vt, attn, ctx16);

  proj_out_kernel<<<dim3(64, 8), blk, 0, stream>>>(
      ctx16, WtHi4 + 3 * WSTRIDE, WtLo4 + 3 * WSTRIDE, bo, out);
}